// Round 1
// baseline (2998.856 us; speedup 1.0000x reference)
//
#include <hip/hip_runtime.h>

#define N_NODES 100000
#define E_EDGES 1600000
#define IN_F    128
#define HID_F   64
#define OUT_F   64
#define BN_EPS  1e-5f

// ---------------------------------------------------------------------------
// 1. degree accumulation: deg[dst] += 1 per edge
__global__ __launch_bounds__(256) void k_deg(const int* __restrict__ dstv,
                                             float* __restrict__ deg) {
    int e = blockIdx.x * 256 + threadIdx.x;
    if (e < E_EDGES) unsafeAtomicAdd(&deg[dstv[e]], 1.0f);
}

// 2. dis[i] = rsqrt(deg[i] + 1)   (in place)
__global__ __launch_bounds__(256) void k_dis(float* __restrict__ deg_dis) {
    int i = blockIdx.x * 256 + threadIdx.x;
    if (i < N_NODES) deg_dis[i] = rsqrtf(deg_dis[i] + 1.0f);
}

// ---------------------------------------------------------------------------
// 3. hs1 = dis * (x @ W1);  x [N][128], W1 [128][64], out [N][64]
//    64-row tile, 256 threads, per-thread 4x4 register tile, K split in 2.
__global__ __launch_bounds__(256) void k_gemm1(const float* __restrict__ x,
                                               const float* __restrict__ W1,
                                               const float* __restrict__ dis,
                                               float* __restrict__ hs1) {
    __shared__ float Ws[IN_F][HID_F];   // 32 KB
    __shared__ float As[64][68];        // 17 KB (pad 68: 16B-aligned rows, 2-way bank max)
    const int tid = threadIdx.x;
    const int r0 = blockIdx.x * 64;

    // stage W1: 8192 floats = 2048 float4
#pragma unroll
    for (int p = 0; p < 8; ++p) {
        int idx = p * 256 + tid;
        ((float4*)&Ws[0][0])[idx] = ((const float4*)W1)[idx];
    }

    const int tx = tid & 15, ty = tid >> 4;
    float acc[4][4] = {};

    for (int kk = 0; kk < IN_F; kk += 64) {
        __syncthreads();
        // stage A half-tile: 64 rows x 64 k = 1024 float4
#pragma unroll
        for (int p = 0; p < 4; ++p) {
            int idx = p * 256 + tid;
            int row = idx >> 4;     // 16 float4 per row-half
            int c4  = idx & 15;
            float4 v = make_float4(0.f, 0.f, 0.f, 0.f);
            if (r0 + row < N_NODES)
                v = ((const float4*)(x + (size_t)(r0 + row) * IN_F + kk))[c4];
            *(float4*)&As[row][c4 * 4] = v;
        }
        __syncthreads();
#pragma unroll 4
        for (int k2 = 0; k2 < 64; ++k2) {
            int k = kk + k2;
            float4 b = *(const float4*)&Ws[k][tx * 4];
            float a0 = As[ty * 4 + 0][k2];
            float a1 = As[ty * 4 + 1][k2];
            float a2 = As[ty * 4 + 2][k2];
            float a3 = As[ty * 4 + 3][k2];
            acc[0][0] = fmaf(a0, b.x, acc[0][0]); acc[0][1] = fmaf(a0, b.y, acc[0][1]);
            acc[0][2] = fmaf(a0, b.z, acc[0][2]); acc[0][3] = fmaf(a0, b.w, acc[0][3]);
            acc[1][0] = fmaf(a1, b.x, acc[1][0]); acc[1][1] = fmaf(a1, b.y, acc[1][1]);
            acc[1][2] = fmaf(a1, b.z, acc[1][2]); acc[1][3] = fmaf(a1, b.w, acc[1][3]);
            acc[2][0] = fmaf(a2, b.x, acc[2][0]); acc[2][1] = fmaf(a2, b.y, acc[2][1]);
            acc[2][2] = fmaf(a2, b.z, acc[2][2]); acc[2][3] = fmaf(a2, b.w, acc[2][3]);
            acc[3][0] = fmaf(a3, b.x, acc[3][0]); acc[3][1] = fmaf(a3, b.y, acc[3][1]);
            acc[3][2] = fmaf(a3, b.z, acc[3][2]); acc[3][3] = fmaf(a3, b.w, acc[3][3]);
        }
    }
#pragma unroll
    for (int j = 0; j < 4; ++j) {
        int row = r0 + ty * 4 + j;
        if (row < N_NODES) {
            float d = dis[row];
            float4 o;
            o.x = acc[j][0] * d; o.y = acc[j][1] * d;
            o.z = acc[j][2] * d; o.w = acc[j][3] * d;
            *(float4*)(hs1 + (size_t)row * HID_F + tx * 4) = o;
        }
    }
}

// ---------------------------------------------------------------------------
// 4. scatter: tmp[dst] += hs[src] (64 floats per edge, 16 threads/edge)
__global__ __launch_bounds__(256) void k_scatter(const int* __restrict__ srcv,
                                                 const int* __restrict__ dstv,
                                                 const float* __restrict__ hs,
                                                 float* __restrict__ tmp) {
    __shared__ int se[16], de[16];
    const int tid = threadIdx.x;
    const long long base_e = (long long)blockIdx.x * 16;
    if (tid < 16) {
        long long e = base_e + tid;
        if (e < E_EDGES) { se[tid] = srcv[e]; de[tid] = dstv[e]; }
    }
    __syncthreads();
    const int le = tid >> 4, q = tid & 15;
    long long e = base_e + le;
    if (e < E_EDGES) {
        int s = se[le], d = de[le];
        float4 v = ((const float4*)(hs + (size_t)s * HID_F))[q];
        float* t = tmp + (size_t)d * HID_F + q * 4;
        unsafeAtomicAdd(t + 0, v.x);
        unsafeAtomicAdd(t + 1, v.y);
        unsafeAtomicAdd(t + 2, v.z);
        unsafeAtomicAdd(t + 3, v.w);
    }
}

// ---------------------------------------------------------------------------
// 5. epilogue conv1 (in place on agg) + BN statistics accumulation
//    agg1 = dis[row]*(tmp1 + hs1) + b1[col]; bnstats[col] += v; bnstats[64+col] += v*v
__global__ __launch_bounds__(256) void k_final1(float* __restrict__ agg,
                                                const float* __restrict__ hs1,
                                                const float* __restrict__ dis,
                                                const float* __restrict__ b1,
                                                float* __restrict__ bnstats) {
    __shared__ float red[256];
    const int tid = threadIdx.x;
    const int col = tid & 63;
    const float bc = b1[col];
    float s = 0.f, sq = 0.f;
    const int total = N_NODES * HID_F;
    const int stride = gridDim.x * 256;   // multiple of 64 -> col invariant
    for (int i = blockIdx.x * 256 + tid; i < total; i += stride) {
        int row = i >> 6;
        float v = fmaf(dis[row], agg[i] + hs1[i], bc);
        agg[i] = v;
        s += v;
        sq = fmaf(v, v, sq);
    }
    red[tid] = s;
    __syncthreads();
    if (tid < 64) {
        s = red[tid] + red[tid + 64] + red[tid + 128] + red[tid + 192];
        unsafeAtomicAdd(&bnstats[tid], s);
    }
    __syncthreads();
    red[tid] = sq;
    __syncthreads();
    if (tid < 64) {
        sq = red[tid] + red[tid + 64] + red[tid + 128] + red[tid + 192];
        unsafeAtomicAdd(&bnstats[64 + tid], sq);
    }
}

// ---------------------------------------------------------------------------
// 6. hs2 = dis * (relu(BN(agg1)) @ W2)
__global__ __launch_bounds__(256) void k_gemm2(const float* __restrict__ agg1,
                                               const float* __restrict__ W2,
                                               const float* __restrict__ dis,
                                               const float* __restrict__ bnw,
                                               const float* __restrict__ bnb,
                                               const float* __restrict__ bnstats,
                                               float* __restrict__ hs2) {
    __shared__ float Ws[HID_F][OUT_F];  // 16 KB
    __shared__ float As[64][68];        // 17 KB
    __shared__ float scale_s[64], shift_s[64];
    const int tid = threadIdx.x;
    const int r0 = blockIdx.x * 64;

    if (tid < 64) {
        const float invN = 1.0f / (float)N_NODES;
        float mean = bnstats[tid] * invN;
        float var  = bnstats[64 + tid] * invN - mean * mean;
        float sc   = bnw[tid] * rsqrtf(var + BN_EPS);
        scale_s[tid] = sc;
        shift_s[tid] = fmaf(-mean, sc, bnb[tid]);
    }
#pragma unroll
    for (int p = 0; p < 4; ++p) {
        int idx = p * 256 + tid;
        ((float4*)&Ws[0][0])[idx] = ((const float4*)W2)[idx];
    }
    __syncthreads();
#pragma unroll
    for (int p = 0; p < 4; ++p) {
        int idx = p * 256 + tid;
        int row = idx >> 4;
        int c4  = idx & 15;
        float4 v = make_float4(0.f, 0.f, 0.f, 0.f);
        if (r0 + row < N_NODES) {
            v = ((const float4*)(agg1 + (size_t)(r0 + row) * HID_F))[c4];
            int k0 = c4 * 4;
            v.x = fmaxf(fmaf(v.x, scale_s[k0 + 0], shift_s[k0 + 0]), 0.f);
            v.y = fmaxf(fmaf(v.y, scale_s[k0 + 1], shift_s[k0 + 1]), 0.f);
            v.z = fmaxf(fmaf(v.z, scale_s[k0 + 2], shift_s[k0 + 2]), 0.f);
            v.w = fmaxf(fmaf(v.w, scale_s[k0 + 3], shift_s[k0 + 3]), 0.f);
        }
        *(float4*)&As[row][c4 * 4] = v;
    }
    __syncthreads();
    const int tx = tid & 15, ty = tid >> 4;
    float acc[4][4] = {};
#pragma unroll 4
    for (int k = 0; k < HID_F; ++k) {
        float4 b = *(const float4*)&Ws[k][tx * 4];
        float a0 = As[ty * 4 + 0][k];
        float a1 = As[ty * 4 + 1][k];
        float a2 = As[ty * 4 + 2][k];
        float a3 = As[ty * 4 + 3][k];
        acc[0][0] = fmaf(a0, b.x, acc[0][0]); acc[0][1] = fmaf(a0, b.y, acc[0][1]);
        acc[0][2] = fmaf(a0, b.z, acc[0][2]); acc[0][3] = fmaf(a0, b.w, acc[0][3]);
        acc[1][0] = fmaf(a1, b.x, acc[1][0]); acc[1][1] = fmaf(a1, b.y, acc[1][1]);
        acc[1][2] = fmaf(a1, b.z, acc[1][2]); acc[1][3] = fmaf(a1, b.w, acc[1][3]);
        acc[2][0] = fmaf(a2, b.x, acc[2][0]); acc[2][1] = fmaf(a2, b.y, acc[2][1]);
        acc[2][2] = fmaf(a2, b.z, acc[2][2]); acc[2][3] = fmaf(a2, b.w, acc[2][3]);
        acc[3][0] = fmaf(a3, b.x, acc[3][0]); acc[3][1] = fmaf(a3, b.y, acc[3][1]);
        acc[3][2] = fmaf(a3, b.z, acc[3][2]); acc[3][3] = fmaf(a3, b.w, acc[3][3]);
    }
#pragma unroll
    for (int j = 0; j < 4; ++j) {
        int row = r0 + ty * 4 + j;
        if (row < N_NODES) {
            float d = dis[row];
            float4 o;
            o.x = acc[j][0] * d; o.y = acc[j][1] * d;
            o.z = acc[j][2] * d; o.w = acc[j][3] * d;
            *(float4*)(hs2 + (size_t)row * OUT_F + tx * 4) = o;
        }
    }
}

// ---------------------------------------------------------------------------
// 7. final epilogue: out = dis[row]*(tmp2 + hs2) + b2[col]  (in place on out)
__global__ __launch_bounds__(256) void k_final2(float* __restrict__ out,
                                                const float* __restrict__ hs2,
                                                const float* __restrict__ dis,
                                                const float* __restrict__ b2) {
    int i = blockIdx.x * 256 + threadIdx.x;
    if (i < N_NODES * OUT_F) {
        int row = i >> 6, col = i & 63;
        out[i] = fmaf(dis[row], out[i] + hs2[i], b2[col]);
    }
}

// ---------------------------------------------------------------------------
extern "C" void kernel_launch(void* const* d_in, const int* in_sizes, int n_in,
                              void* d_out, int out_size, void* d_ws, size_t ws_size,
                              hipStream_t stream) {
    const float* x   = (const float*)d_in[0];
    const int*   ei  = (const int*)d_in[1];
    const float* W1  = (const float*)d_in[2];
    const float* b1  = (const float*)d_in[3];
    const float* bnw = (const float*)d_in[4];
    const float* bnb = (const float*)d_in[5];
    const float* W2  = (const float*)d_in[6];
    const float* b2  = (const float*)d_in[7];
    float* out = (float*)d_out;

    // workspace layout (floats): dis[N] | bufA[N*64] | bufB[N*64] | bnstats[128]
    float* ws      = (float*)d_ws;
    float* dis     = ws;                       // N (also deg during accumulation)
    float* bufA    = ws + 100352;              // 16B-aligned; hs1 then hs2
    float* bufB    = bufA + (size_t)N_NODES * HID_F;  // tmp1 then agg1
    float* bnstats = bufB + (size_t)N_NODES * HID_F;  // 64 sum + 64 sumsq

    const int* srcv = ei;
    const int* dstv = ei + E_EDGES;

    hipMemsetAsync(dis, 0, N_NODES * sizeof(float), stream);
    hipMemsetAsync(bufB, 0, (size_t)N_NODES * HID_F * sizeof(float), stream);
    hipMemsetAsync(bnstats, 0, 128 * sizeof(float), stream);
    hipMemsetAsync(out, 0, (size_t)N_NODES * OUT_F * sizeof(float), stream);

    k_deg<<<(E_EDGES + 255) / 256, 256, 0, stream>>>(dstv, dis);
    k_dis<<<(N_NODES + 255) / 256, 256, 0, stream>>>(dis);
    k_gemm1<<<(N_NODES + 63) / 64, 256, 0, stream>>>(x, W1, dis, bufA);
    k_scatter<<<(E_EDGES + 15) / 16, 256, 0, stream>>>(srcv, dstv, bufA, bufB);
    k_final1<<<1024, 256, 0, stream>>>(bufB, bufA, dis, b1, bnstats);
    k_gemm2<<<(N_NODES + 63) / 64, 256, 0, stream>>>(bufB, W2, dis, bnw, bnb, bnstats, bufA);
    k_scatter<<<(E_EDGES + 15) / 16, 256, 0, stream>>>(srcv, dstv, bufA, out);
    k_final2<<<(N_NODES * OUT_F + 255) / 256, 256, 0, stream>>>(out, bufA, dis, b2);
}

// Round 2
// 580.381 us; speedup vs baseline: 5.1671x; 5.1671x over previous
//
#include <hip/hip_runtime.h>

#define N_NODES 100000
#define E_EDGES 1600000
#define IN_F    128
#define HID_F   64
#define OUT_F   64
#define BN_EPS  1e-5f
#define NB_SCAN 391   // ceil(N/256)

// ---------------------------------------------------------------------------
// 1. int histogram of dst: cnt[dst]++
__global__ __launch_bounds__(256) void k_hist(const int* __restrict__ dstv,
                                              int* __restrict__ cnt) {
    int e = blockIdx.x * 256 + threadIdx.x;
    if (e < E_EDGES) atomicAdd(&cnt[dstv[e]], 1);
}

// 2. dis[i] = rsqrt(cnt[i] + 1)
__global__ __launch_bounds__(256) void k_dis(const int* __restrict__ cnt,
                                             float* __restrict__ dis) {
    int i = blockIdx.x * 256 + threadIdx.x;
    if (i < N_NODES) dis[i] = rsqrtf((float)cnt[i] + 1.0f);
}

// 3a. per-block sums of cnt
__global__ __launch_bounds__(256) void k_scan1(const int* __restrict__ cnt,
                                               int* __restrict__ bsum) {
    __shared__ int sh[256];
    int tid = threadIdx.x;
    int i = blockIdx.x * 256 + tid;
    sh[tid] = (i < N_NODES) ? cnt[i] : 0;
    __syncthreads();
    for (int s = 128; s > 0; s >>= 1) {
        if (tid < s) sh[tid] += sh[tid + s];
        __syncthreads();
    }
    if (tid == 0) bsum[blockIdx.x] = sh[0];
}

// 3b. exclusive scan of block sums (one block of 512), plus row_ptr[N]=E
__global__ __launch_bounds__(512) void k_scan2(int* __restrict__ bsum,
                                               int* __restrict__ rowptr) {
    __shared__ int sh[512];
    int tid = threadIdx.x;
    int v = (tid < NB_SCAN) ? bsum[tid] : 0;
    sh[tid] = v;
    __syncthreads();
    for (int off = 1; off < 512; off <<= 1) {
        int t = (tid >= off) ? sh[tid - off] : 0;
        __syncthreads();
        sh[tid] += t;
        __syncthreads();
    }
    if (tid < NB_SCAN) bsum[tid] = sh[tid] - v;   // exclusive
    if (tid == 0) rowptr[N_NODES] = E_EDGES;
}

// 3c. block-local exclusive scan + offset -> row_ptr (in place over cnt) + cursor
__global__ __launch_bounds__(256) void k_scan3(int* __restrict__ cnt_rowptr,
                                               const int* __restrict__ bsum,
                                               int* __restrict__ cursor) {
    __shared__ int sh[256];
    int tid = threadIdx.x;
    int i = blockIdx.x * 256 + tid;
    int v = (i < N_NODES) ? cnt_rowptr[i] : 0;
    sh[tid] = v;
    __syncthreads();
    for (int off = 1; off < 256; off <<= 1) {
        int t = (tid >= off) ? sh[tid - off] : 0;
        __syncthreads();
        sh[tid] += t;
        __syncthreads();
    }
    if (i < N_NODES) {
        int p = bsum[blockIdx.x] + sh[tid] - v;   // exclusive prefix
        cnt_rowptr[i] = p;
        cursor[i]     = p;
    }
}

// 4. fill CSR: csr_src[pos] = src   (pos = cursor[dst]++)
__global__ __launch_bounds__(256) void k_fill(const int* __restrict__ srcv,
                                              const int* __restrict__ dstv,
                                              int* __restrict__ cursor,
                                              int* __restrict__ csr_src) {
    int e = blockIdx.x * 256 + threadIdx.x;
    if (e < E_EDGES) {
        int d = dstv[e];
        int pos = atomicAdd(&cursor[d], 1);
        csr_src[pos] = srcv[e];
    }
}

// ---------------------------------------------------------------------------
// 5. hs1 = dis * (x @ W1)
__global__ __launch_bounds__(256) void k_gemm1(const float* __restrict__ x,
                                               const float* __restrict__ W1,
                                               const float* __restrict__ dis,
                                               float* __restrict__ hs1) {
    __shared__ float Ws[IN_F][HID_F];
    __shared__ float As[64][68];
    const int tid = threadIdx.x;
    const int r0 = blockIdx.x * 64;

#pragma unroll
    for (int p = 0; p < 8; ++p) {
        int idx = p * 256 + tid;
        ((float4*)&Ws[0][0])[idx] = ((const float4*)W1)[idx];
    }

    const int tx = tid & 15, ty = tid >> 4;
    float acc[4][4] = {};

    for (int kk = 0; kk < IN_F; kk += 64) {
        __syncthreads();
#pragma unroll
        for (int p = 0; p < 4; ++p) {
            int idx = p * 256 + tid;
            int row = idx >> 4;
            int c4  = idx & 15;
            float4 v = make_float4(0.f, 0.f, 0.f, 0.f);
            if (r0 + row < N_NODES)
                v = ((const float4*)(x + (size_t)(r0 + row) * IN_F + kk))[c4];
            *(float4*)&As[row][c4 * 4] = v;
        }
        __syncthreads();
#pragma unroll 4
        for (int k2 = 0; k2 < 64; ++k2) {
            int k = kk + k2;
            float4 b = *(const float4*)&Ws[k][tx * 4];
            float a0 = As[ty * 4 + 0][k2];
            float a1 = As[ty * 4 + 1][k2];
            float a2 = As[ty * 4 + 2][k2];
            float a3 = As[ty * 4 + 3][k2];
            acc[0][0] = fmaf(a0, b.x, acc[0][0]); acc[0][1] = fmaf(a0, b.y, acc[0][1]);
            acc[0][2] = fmaf(a0, b.z, acc[0][2]); acc[0][3] = fmaf(a0, b.w, acc[0][3]);
            acc[1][0] = fmaf(a1, b.x, acc[1][0]); acc[1][1] = fmaf(a1, b.y, acc[1][1]);
            acc[1][2] = fmaf(a1, b.z, acc[1][2]); acc[1][3] = fmaf(a1, b.w, acc[1][3]);
            acc[2][0] = fmaf(a2, b.x, acc[2][0]); acc[2][1] = fmaf(a2, b.y, acc[2][1]);
            acc[2][2] = fmaf(a2, b.z, acc[2][2]); acc[2][3] = fmaf(a2, b.w, acc[2][3]);
            acc[3][0] = fmaf(a3, b.x, acc[3][0]); acc[3][1] = fmaf(a3, b.y, acc[3][1]);
            acc[3][2] = fmaf(a3, b.z, acc[3][2]); acc[3][3] = fmaf(a3, b.w, acc[3][3]);
        }
    }
#pragma unroll
    for (int j = 0; j < 4; ++j) {
        int row = r0 + ty * 4 + j;
        if (row < N_NODES) {
            float d = dis[row];
            float4 o;
            o.x = acc[j][0] * d; o.y = acc[j][1] * d;
            o.z = acc[j][2] * d; o.w = acc[j][3] * d;
            *(float4*)(hs1 + (size_t)row * HID_F + tx * 4) = o;
        }
    }
}

// ---------------------------------------------------------------------------
// 6. gather conv1 + epilogue + BN-stats:
//    agg[n] = dis[n]*(sum_{s in N(n)} hs1[s] + hs1[n]) + b1 ; stats += agg
__global__ __launch_bounds__(256) void k_gather1(const int* __restrict__ rowptr,
                                                 const int* __restrict__ csr_src,
                                                 const float* __restrict__ hs1,
                                                 const float* __restrict__ dis,
                                                 const float* __restrict__ b1,
                                                 float* __restrict__ agg,
                                                 float* __restrict__ bnstats) {
    const int tid = threadIdx.x;
    const int g = tid >> 4, q = tid & 15;
    const float4 bc = ((const float4*)b1)[q];
    float4 bsum = make_float4(0.f, 0.f, 0.f, 0.f);
    float4 bsq  = make_float4(0.f, 0.f, 0.f, 0.f);

    const int ngroups = N_NODES / 16;  // 6250 exactly
    for (int blk = blockIdx.x; blk < ngroups; blk += gridDim.x) {
        int n = blk * 16 + g;
        int start = rowptr[n], end = rowptr[n + 1];
        float4 a0 = ((const float4*)(hs1 + (size_t)n * HID_F))[q];  // self term
        float4 a1 = make_float4(0.f, 0.f, 0.f, 0.f);
        int i = start;
        for (; i + 1 < end; i += 2) {
            int s0 = csr_src[i], s1 = csr_src[i + 1];
            float4 v0 = ((const float4*)(hs1 + (size_t)s0 * HID_F))[q];
            float4 v1 = ((const float4*)(hs1 + (size_t)s1 * HID_F))[q];
            a0.x += v0.x; a0.y += v0.y; a0.z += v0.z; a0.w += v0.w;
            a1.x += v1.x; a1.y += v1.y; a1.z += v1.z; a1.w += v1.w;
        }
        if (i < end) {
            int s0 = csr_src[i];
            float4 v0 = ((const float4*)(hs1 + (size_t)s0 * HID_F))[q];
            a0.x += v0.x; a0.y += v0.y; a0.z += v0.z; a0.w += v0.w;
        }
        float d = dis[n];
        float4 o;
        o.x = fmaf(d, a0.x + a1.x, bc.x);
        o.y = fmaf(d, a0.y + a1.y, bc.y);
        o.z = fmaf(d, a0.z + a1.z, bc.z);
        o.w = fmaf(d, a0.w + a1.w, bc.w);
        ((float4*)(agg + (size_t)n * HID_F))[q] = o;
        bsum.x += o.x; bsum.y += o.y; bsum.z += o.z; bsum.w += o.w;
        bsq.x = fmaf(o.x, o.x, bsq.x); bsq.y = fmaf(o.y, o.y, bsq.y);
        bsq.z = fmaf(o.z, o.z, bsq.z); bsq.w = fmaf(o.w, o.w, bsq.w);
    }

    __shared__ float4 red[256];
    red[tid] = bsum;
    __syncthreads();
    for (int s = 128; s >= 16; s >>= 1) {
        if (tid < s) {
            red[tid].x += red[tid + s].x; red[tid].y += red[tid + s].y;
            red[tid].z += red[tid + s].z; red[tid].w += red[tid + s].w;
        }
        __syncthreads();
    }
    if (tid < 16) {
        float4 r = red[tid];
        unsafeAtomicAdd(&bnstats[tid * 4 + 0], r.x);
        unsafeAtomicAdd(&bnstats[tid * 4 + 1], r.y);
        unsafeAtomicAdd(&bnstats[tid * 4 + 2], r.z);
        unsafeAtomicAdd(&bnstats[tid * 4 + 3], r.w);
    }
    __syncthreads();
    red[tid] = bsq;
    __syncthreads();
    for (int s = 128; s >= 16; s >>= 1) {
        if (tid < s) {
            red[tid].x += red[tid + s].x; red[tid].y += red[tid + s].y;
            red[tid].z += red[tid + s].z; red[tid].w += red[tid + s].w;
        }
        __syncthreads();
    }
    if (tid < 16) {
        float4 r = red[tid];
        unsafeAtomicAdd(&bnstats[64 + tid * 4 + 0], r.x);
        unsafeAtomicAdd(&bnstats[64 + tid * 4 + 1], r.y);
        unsafeAtomicAdd(&bnstats[64 + tid * 4 + 2], r.z);
        unsafeAtomicAdd(&bnstats[64 + tid * 4 + 3], r.w);
    }
}

// ---------------------------------------------------------------------------
// 7. hs2 = dis * (relu(BN(agg1)) @ W2)
__global__ __launch_bounds__(256) void k_gemm2(const float* __restrict__ agg1,
                                               const float* __restrict__ W2,
                                               const float* __restrict__ dis,
                                               const float* __restrict__ bnw,
                                               const float* __restrict__ bnb,
                                               const float* __restrict__ bnstats,
                                               float* __restrict__ hs2) {
    __shared__ float Ws[HID_F][OUT_F];
    __shared__ float As[64][68];
    __shared__ float scale_s[64], shift_s[64];
    const int tid = threadIdx.x;
    const int r0 = blockIdx.x * 64;

    if (tid < 64) {
        const float invN = 1.0f / (float)N_NODES;
        float mean = bnstats[tid] * invN;
        float var  = bnstats[64 + tid] * invN - mean * mean;
        float sc   = bnw[tid] * rsqrtf(var + BN_EPS);
        scale_s[tid] = sc;
        shift_s[tid] = fmaf(-mean, sc, bnb[tid]);
    }
#pragma unroll
    for (int p = 0; p < 4; ++p) {
        int idx = p * 256 + tid;
        ((float4*)&Ws[0][0])[idx] = ((const float4*)W2)[idx];
    }
    __syncthreads();
#pragma unroll
    for (int p = 0; p < 4; ++p) {
        int idx = p * 256 + tid;
        int row = idx >> 4;
        int c4  = idx & 15;
        float4 v = make_float4(0.f, 0.f, 0.f, 0.f);
        if (r0 + row < N_NODES) {
            v = ((const float4*)(agg1 + (size_t)(r0 + row) * HID_F))[c4];
            int k0 = c4 * 4;
            v.x = fmaxf(fmaf(v.x, scale_s[k0 + 0], shift_s[k0 + 0]), 0.f);
            v.y = fmaxf(fmaf(v.y, scale_s[k0 + 1], shift_s[k0 + 1]), 0.f);
            v.z = fmaxf(fmaf(v.z, scale_s[k0 + 2], shift_s[k0 + 2]), 0.f);
            v.w = fmaxf(fmaf(v.w, scale_s[k0 + 3], shift_s[k0 + 3]), 0.f);
        }
        *(float4*)&As[row][c4 * 4] = v;
    }
    __syncthreads();
    const int tx = tid & 15, ty = tid >> 4;
    float acc[4][4] = {};
#pragma unroll 4
    for (int k = 0; k < HID_F; ++k) {
        float4 b = *(const float4*)&Ws[k][tx * 4];
        float a0 = As[ty * 4 + 0][k];
        float a1 = As[ty * 4 + 1][k];
        float a2 = As[ty * 4 + 2][k];
        float a3 = As[ty * 4 + 3][k];
        acc[0][0] = fmaf(a0, b.x, acc[0][0]); acc[0][1] = fmaf(a0, b.y, acc[0][1]);
        acc[0][2] = fmaf(a0, b.z, acc[0][2]); acc[0][3] = fmaf(a0, b.w, acc[0][3]);
        acc[1][0] = fmaf(a1, b.x, acc[1][0]); acc[1][1] = fmaf(a1, b.y, acc[1][1]);
        acc[1][2] = fmaf(a1, b.z, acc[1][2]); acc[1][3] = fmaf(a1, b.w, acc[1][3]);
        acc[2][0] = fmaf(a2, b.x, acc[2][0]); acc[2][1] = fmaf(a2, b.y, acc[2][1]);
        acc[2][2] = fmaf(a2, b.z, acc[2][2]); acc[2][3] = fmaf(a2, b.w, acc[2][3]);
        acc[3][0] = fmaf(a3, b.x, acc[3][0]); acc[3][1] = fmaf(a3, b.y, acc[3][1]);
        acc[3][2] = fmaf(a3, b.z, acc[3][2]); acc[3][3] = fmaf(a3, b.w, acc[3][3]);
    }
#pragma unroll
    for (int j = 0; j < 4; ++j) {
        int row = r0 + ty * 4 + j;
        if (row < N_NODES) {
            float d = dis[row];
            float4 o;
            o.x = acc[j][0] * d; o.y = acc[j][1] * d;
            o.z = acc[j][2] * d; o.w = acc[j][3] * d;
            *(float4*)(hs2 + (size_t)row * OUT_F + tx * 4) = o;
        }
    }
}

// ---------------------------------------------------------------------------
// 8. gather conv2 + final epilogue: out[n] = dis[n]*(sum + hs2[n]) + b2
__global__ __launch_bounds__(256) void k_gather2(const int* __restrict__ rowptr,
                                                 const int* __restrict__ csr_src,
                                                 const float* __restrict__ hs2,
                                                 const float* __restrict__ dis,
                                                 const float* __restrict__ b2,
                                                 float* __restrict__ out) {
    const int tid = threadIdx.x;
    const int g = tid >> 4, q = tid & 15;
    const float4 bc = ((const float4*)b2)[q];

    const int ngroups = N_NODES / 16;
    for (int blk = blockIdx.x; blk < ngroups; blk += gridDim.x) {
        int n = blk * 16 + g;
        int start = rowptr[n], end = rowptr[n + 1];
        float4 a0 = ((const float4*)(hs2 + (size_t)n * OUT_F))[q];
        float4 a1 = make_float4(0.f, 0.f, 0.f, 0.f);
        int i = start;
        for (; i + 1 < end; i += 2) {
            int s0 = csr_src[i], s1 = csr_src[i + 1];
            float4 v0 = ((const float4*)(hs2 + (size_t)s0 * OUT_F))[q];
            float4 v1 = ((const float4*)(hs2 + (size_t)s1 * OUT_F))[q];
            a0.x += v0.x; a0.y += v0.y; a0.z += v0.z; a0.w += v0.w;
            a1.x += v1.x; a1.y += v1.y; a1.z += v1.z; a1.w += v1.w;
        }
        if (i < end) {
            int s0 = csr_src[i];
            float4 v0 = ((const float4*)(hs2 + (size_t)s0 * OUT_F))[q];
            a0.x += v0.x; a0.y += v0.y; a0.z += v0.z; a0.w += v0.w;
        }
        float d = dis[n];
        float4 o;
        o.x = fmaf(d, a0.x + a1.x, bc.x);
        o.y = fmaf(d, a0.y + a1.y, bc.y);
        o.z = fmaf(d, a0.z + a1.z, bc.z);
        o.w = fmaf(d, a0.w + a1.w, bc.w);
        ((float4*)(out + (size_t)n * OUT_F))[q] = o;
    }
}

// ---------------------------------------------------------------------------
extern "C" void kernel_launch(void* const* d_in, const int* in_sizes, int n_in,
                              void* d_out, int out_size, void* d_ws, size_t ws_size,
                              hipStream_t stream) {
    const float* x   = (const float*)d_in[0];
    const int*   ei  = (const int*)d_in[1];
    const float* W1  = (const float*)d_in[2];
    const float* b1  = (const float*)d_in[3];
    const float* bnw = (const float*)d_in[4];
    const float* bnb = (const float*)d_in[5];
    const float* W2  = (const float*)d_in[6];
    const float* b2  = (const float*)d_in[7];
    float* out = (float*)d_out;

    // workspace layout (4-byte units, 16B-aligned segments):
    float* ws = (float*)d_ws;
    float* dis       = ws;                                 // 100352 floats
    int*   cnt_rp    = (int*)(ws + 100352);                // 100608 ints (cnt -> row_ptr)
    int*   cursor    = (int*)(ws + 100352 + 100608);       // 100352 ints
    int*   bsum      = (int*)(ws + 100352 + 100608 + 100352);        // 512 ints
    float* bnstats   = ws + 100352 + 100608 + 100352 + 512;          // 128 floats
    int*   csr_src   = (int*)(ws + 100352 + 100608 + 100352 + 512 + 128); // 1.6M ints
    float* bufA      = ws + 100352 + 100608 + 100352 + 512 + 128 + 1600000;   // N*64
    float* bufB      = bufA + (size_t)N_NODES * HID_F;                        // N*64

    const int* srcv = ei;
    const int* dstv = ei + E_EDGES;

    hipMemsetAsync(cnt_rp, 0, (N_NODES + 1) * sizeof(int), stream);
    hipMemsetAsync(bnstats, 0, 128 * sizeof(float), stream);

    k_hist <<<(E_EDGES + 255) / 256, 256, 0, stream>>>(dstv, cnt_rp);
    k_dis  <<<NB_SCAN, 256, 0, stream>>>(cnt_rp, dis);
    k_scan1<<<NB_SCAN, 256, 0, stream>>>(cnt_rp, bsum);
    k_scan2<<<1, 512, 0, stream>>>(bsum, cnt_rp);
    k_scan3<<<NB_SCAN, 256, 0, stream>>>(cnt_rp, bsum, cursor);
    k_fill <<<(E_EDGES + 255) / 256, 256, 0, stream>>>(srcv, dstv, cursor, csr_src);

    k_gemm1<<<(N_NODES + 63) / 64, 256, 0, stream>>>(x, W1, dis, bufA);
    k_gather1<<<1024, 256, 0, stream>>>(cnt_rp, csr_src, bufA, dis, b1, bufB, bnstats);
    k_gemm2<<<(N_NODES + 63) / 64, 256, 0, stream>>>(bufB, W2, dis, bnw, bnb, bnstats, bufA);
    k_gather2<<<1024, 256, 0, stream>>>(cnt_rp, csr_src, bufA, dis, b2, out);
}

// Round 3
// 492.990 us; speedup vs baseline: 6.0830x; 1.1773x over previous
//
#include <hip/hip_runtime.h>

#define N_NODES 100000
#define E_EDGES 1600000
#define IN_F    128
#define HID_F   64
#define OUT_F   64
#define BN_EPS  1e-5f
#define NB_SCAN 391   // ceil(N/256)
#define NGBLK   6250  // N/16 gather blocks

// ---------------------------------------------------------------------------
// 1. int histogram of dst: cnt[dst]++
__global__ __launch_bounds__(256) void k_hist(const int* __restrict__ dstv,
                                              int* __restrict__ cnt) {
    int e = blockIdx.x * 256 + threadIdx.x;
    if (e < E_EDGES) atomicAdd(&cnt[dstv[e]], 1);
}

// 2. dis[i] = rsqrt(cnt[i] + 1)
__global__ __launch_bounds__(256) void k_dis(const int* __restrict__ cnt,
                                             float* __restrict__ dis) {
    int i = blockIdx.x * 256 + threadIdx.x;
    if (i < N_NODES) dis[i] = rsqrtf((float)cnt[i] + 1.0f);
}

// 3a. per-block sums of cnt
__global__ __launch_bounds__(256) void k_scan1(const int* __restrict__ cnt,
                                               int* __restrict__ bsum) {
    __shared__ int sh[256];
    int tid = threadIdx.x;
    int i = blockIdx.x * 256 + tid;
    sh[tid] = (i < N_NODES) ? cnt[i] : 0;
    __syncthreads();
    for (int s = 128; s > 0; s >>= 1) {
        if (tid < s) sh[tid] += sh[tid + s];
        __syncthreads();
    }
    if (tid == 0) bsum[blockIdx.x] = sh[0];
}

// 3b. exclusive scan of block sums (one block of 512), plus row_ptr[N]=E
__global__ __launch_bounds__(512) void k_scan2(int* __restrict__ bsum,
                                               int* __restrict__ rowptr) {
    __shared__ int sh[512];
    int tid = threadIdx.x;
    int v = (tid < NB_SCAN) ? bsum[tid] : 0;
    sh[tid] = v;
    __syncthreads();
    for (int off = 1; off < 512; off <<= 1) {
        int t = (tid >= off) ? sh[tid - off] : 0;
        __syncthreads();
        sh[tid] += t;
        __syncthreads();
    }
    if (tid < NB_SCAN) bsum[tid] = sh[tid] - v;   // exclusive
    if (tid == 0) rowptr[N_NODES] = E_EDGES;
}

// 3c. block-local exclusive scan + offset -> row_ptr (in place over cnt) + cursor
__global__ __launch_bounds__(256) void k_scan3(int* __restrict__ cnt_rowptr,
                                               const int* __restrict__ bsum,
                                               int* __restrict__ cursor) {
    __shared__ int sh[256];
    int tid = threadIdx.x;
    int i = blockIdx.x * 256 + tid;
    int v = (i < N_NODES) ? cnt_rowptr[i] : 0;
    sh[tid] = v;
    __syncthreads();
    for (int off = 1; off < 256; off <<= 1) {
        int t = (tid >= off) ? sh[tid - off] : 0;
        __syncthreads();
        sh[tid] += t;
        __syncthreads();
    }
    if (i < N_NODES) {
        int p = bsum[blockIdx.x] + sh[tid] - v;   // exclusive prefix
        cnt_rowptr[i] = p;
        cursor[i]     = p;
    }
}

// 4. fill CSR: csr_src[pos] = src   (pos = cursor[dst]++)
__global__ __launch_bounds__(256) void k_fill(const int* __restrict__ srcv,
                                              const int* __restrict__ dstv,
                                              int* __restrict__ cursor,
                                              int* __restrict__ csr_src) {
    int e = blockIdx.x * 256 + threadIdx.x;
    if (e < E_EDGES) {
        int d = dstv[e];
        int pos = atomicAdd(&cursor[d], 1);
        csr_src[pos] = srcv[e];
    }
}

// ---------------------------------------------------------------------------
// 5. hs1 = dis * (x @ W1)
__global__ __launch_bounds__(256) void k_gemm1(const float* __restrict__ x,
                                               const float* __restrict__ W1,
                                               const float* __restrict__ dis,
                                               float* __restrict__ hs1) {
    __shared__ float Ws[IN_F][HID_F];
    __shared__ float As[64][68];
    const int tid = threadIdx.x;
    const int r0 = blockIdx.x * 64;

#pragma unroll
    for (int p = 0; p < 8; ++p) {
        int idx = p * 256 + tid;
        ((float4*)&Ws[0][0])[idx] = ((const float4*)W1)[idx];
    }

    const int tx = tid & 15, ty = tid >> 4;
    float acc[4][4] = {};

    for (int kk = 0; kk < IN_F; kk += 64) {
        __syncthreads();
#pragma unroll
        for (int p = 0; p < 4; ++p) {
            int idx = p * 256 + tid;
            int row = idx >> 4;
            int c4  = idx & 15;
            float4 v = make_float4(0.f, 0.f, 0.f, 0.f);
            if (r0 + row < N_NODES)
                v = ((const float4*)(x + (size_t)(r0 + row) * IN_F + kk))[c4];
            *(float4*)&As[row][c4 * 4] = v;
        }
        __syncthreads();
#pragma unroll 4
        for (int k2 = 0; k2 < 64; ++k2) {
            int k = kk + k2;
            float4 b = *(const float4*)&Ws[k][tx * 4];
            float a0 = As[ty * 4 + 0][k2];
            float a1 = As[ty * 4 + 1][k2];
            float a2 = As[ty * 4 + 2][k2];
            float a3 = As[ty * 4 + 3][k2];
            acc[0][0] = fmaf(a0, b.x, acc[0][0]); acc[0][1] = fmaf(a0, b.y, acc[0][1]);
            acc[0][2] = fmaf(a0, b.z, acc[0][2]); acc[0][3] = fmaf(a0, b.w, acc[0][3]);
            acc[1][0] = fmaf(a1, b.x, acc[1][0]); acc[1][1] = fmaf(a1, b.y, acc[1][1]);
            acc[1][2] = fmaf(a1, b.z, acc[1][2]); acc[1][3] = fmaf(a1, b.w, acc[1][3]);
            acc[2][0] = fmaf(a2, b.x, acc[2][0]); acc[2][1] = fmaf(a2, b.y, acc[2][1]);
            acc[2][2] = fmaf(a2, b.z, acc[2][2]); acc[2][3] = fmaf(a2, b.w, acc[2][3]);
            acc[3][0] = fmaf(a3, b.x, acc[3][0]); acc[3][1] = fmaf(a3, b.y, acc[3][1]);
            acc[3][2] = fmaf(a3, b.z, acc[3][2]); acc[3][3] = fmaf(a3, b.w, acc[3][3]);
        }
    }
#pragma unroll
    for (int j = 0; j < 4; ++j) {
        int row = r0 + ty * 4 + j;
        if (row < N_NODES) {
            float d = dis[row];
            float4 o;
            o.x = acc[j][0] * d; o.y = acc[j][1] * d;
            o.z = acc[j][2] * d; o.w = acc[j][3] * d;
            *(float4*)(hs1 + (size_t)row * HID_F + tx * 4) = o;
        }
    }
}

// ---------------------------------------------------------------------------
// 6. gather conv1 + epilogue; per-block BN partials (no atomics).
//    8-lane half-row groups: g = tid>>3 (0..31), node = blk*16 + (g>>1),
//    half = g&1, float4-slot cbase = half*8 + (tid&7)  (0..15 over 64 cols)
__global__ __launch_bounds__(256) void k_gather1(const int* __restrict__ rowptr,
                                                 const int* __restrict__ csr_src,
                                                 const float* __restrict__ hs,
                                                 const float* __restrict__ dis,
                                                 const float* __restrict__ b1,
                                                 float* __restrict__ agg,
                                                 float* __restrict__ partials) {
    const int tid = threadIdx.x;
    const int g = tid >> 3;
    const int q = tid & 7;
    const int n = blockIdx.x * 16 + (g >> 1);
    const int cbase = (g & 1) * 8 + q;          // float4 index within 64-col row
    const float4* __restrict__ hs4 = (const float4*)hs;

    const int start = rowptr[n], end = rowptr[n + 1];
    float4 a0 = hs4[(size_t)n * 16 + cbase];    // self term
    float4 a1 = make_float4(0.f, 0.f, 0.f, 0.f);
    float4 a2 = make_float4(0.f, 0.f, 0.f, 0.f);
    float4 a3 = make_float4(0.f, 0.f, 0.f, 0.f);
    int i = start;
    for (; i + 3 < end; i += 4) {
        int s0 = csr_src[i + 0], s1 = csr_src[i + 1];
        int s2 = csr_src[i + 2], s3 = csr_src[i + 3];
        float4 v0 = hs4[(size_t)s0 * 16 + cbase];
        float4 v1 = hs4[(size_t)s1 * 16 + cbase];
        float4 v2 = hs4[(size_t)s2 * 16 + cbase];
        float4 v3 = hs4[(size_t)s3 * 16 + cbase];
        a0.x += v0.x; a0.y += v0.y; a0.z += v0.z; a0.w += v0.w;
        a1.x += v1.x; a1.y += v1.y; a1.z += v1.z; a1.w += v1.w;
        a2.x += v2.x; a2.y += v2.y; a2.z += v2.z; a2.w += v2.w;
        a3.x += v3.x; a3.y += v3.y; a3.z += v3.z; a3.w += v3.w;
    }
    for (; i < end; ++i) {
        int s0 = csr_src[i];
        float4 v0 = hs4[(size_t)s0 * 16 + cbase];
        a0.x += v0.x; a0.y += v0.y; a0.z += v0.z; a0.w += v0.w;
    }
    const float d = dis[n];
    const float4 bc = ((const float4*)b1)[cbase];
    float4 o;
    o.x = fmaf(d, a0.x + a1.x + a2.x + a3.x, bc.x);
    o.y = fmaf(d, a0.y + a1.y + a2.y + a3.y, bc.y);
    o.z = fmaf(d, a0.z + a1.z + a2.z + a3.z, bc.z);
    o.w = fmaf(d, a0.w + a1.w + a2.w + a3.w, bc.w);
    ((float4*)agg)[(size_t)n * 16 + cbase] = o;

    // --- BN partial sums: reduce 16 node-contributions per (half,q) col-quad.
    __shared__ float4 red[256];
    red[tid] = o;
    __syncthreads();
    for (int s = 128; s >= 16; s >>= 1) {
        if (tid < s) {
            red[tid].x += red[tid + s].x; red[tid].y += red[tid + s].y;
            red[tid].z += red[tid + s].z; red[tid].w += red[tid + s].w;
        }
        __syncthreads();
    }
    float4* pr = (float4*)(partials + (size_t)blockIdx.x * 128);
    if (tid < 16) pr[tid] = red[tid];           // sums: floats [0..63]
    __syncthreads();
    float4 sq = make_float4(o.x * o.x, o.y * o.y, o.z * o.z, o.w * o.w);
    red[tid] = sq;
    __syncthreads();
    for (int s = 128; s >= 16; s >>= 1) {
        if (tid < s) {
            red[tid].x += red[tid + s].x; red[tid].y += red[tid + s].y;
            red[tid].z += red[tid + s].z; red[tid].w += red[tid + s].w;
        }
        __syncthreads();
    }
    if (tid < 16) pr[16 + tid] = red[tid];      // sumsq: floats [64..127]
}

// 6b. reduce partials[NGBLK][128] -> bnstats[128]
__global__ __launch_bounds__(256) void k_bnfinal(const float* __restrict__ partials,
                                                 float* __restrict__ bnstats) {
    const int tid = threadIdx.x;
    const int col = tid & 127;
    const int half = tid >> 7;
    float s = 0.f;
    for (int r = blockIdx.x * 2 + half; r < NGBLK; r += 128)
        s += partials[(size_t)r * 128 + col];
    __shared__ float sh[256];
    sh[tid] = s;
    __syncthreads();
    if (tid < 128) unsafeAtomicAdd(&bnstats[col], sh[tid] + sh[tid + 128]);
}

// ---------------------------------------------------------------------------
// 7. hs2 = dis * (relu(BN(agg1)) @ W2)
__global__ __launch_bounds__(256) void k_gemm2(const float* __restrict__ agg1,
                                               const float* __restrict__ W2,
                                               const float* __restrict__ dis,
                                               const float* __restrict__ bnw,
                                               const float* __restrict__ bnb,
                                               const float* __restrict__ bnstats,
                                               float* __restrict__ hs2) {
    __shared__ float Ws[HID_F][OUT_F];
    __shared__ float As[64][68];
    __shared__ float scale_s[64], shift_s[64];
    const int tid = threadIdx.x;
    const int r0 = blockIdx.x * 64;

    if (tid < 64) {
        const float invN = 1.0f / (float)N_NODES;
        float mean = bnstats[tid] * invN;
        float var  = bnstats[64 + tid] * invN - mean * mean;
        float sc   = bnw[tid] * rsqrtf(var + BN_EPS);
        scale_s[tid] = sc;
        shift_s[tid] = fmaf(-mean, sc, bnb[tid]);
    }
#pragma unroll
    for (int p = 0; p < 4; ++p) {
        int idx = p * 256 + tid;
        ((float4*)&Ws[0][0])[idx] = ((const float4*)W2)[idx];
    }
    __syncthreads();
#pragma unroll
    for (int p = 0; p < 4; ++p) {
        int idx = p * 256 + tid;
        int row = idx >> 4;
        int c4  = idx & 15;
        float4 v = make_float4(0.f, 0.f, 0.f, 0.f);
        if (r0 + row < N_NODES) {
            v = ((const float4*)(agg1 + (size_t)(r0 + row) * HID_F))[c4];
            int k0 = c4 * 4;
            v.x = fmaxf(fmaf(v.x, scale_s[k0 + 0], shift_s[k0 + 0]), 0.f);
            v.y = fmaxf(fmaf(v.y, scale_s[k0 + 1], shift_s[k0 + 1]), 0.f);
            v.z = fmaxf(fmaf(v.z, scale_s[k0 + 2], shift_s[k0 + 2]), 0.f);
            v.w = fmaxf(fmaf(v.w, scale_s[k0 + 3], shift_s[k0 + 3]), 0.f);
        }
        *(float4*)&As[row][c4 * 4] = v;
    }
    __syncthreads();
    const int tx = tid & 15, ty = tid >> 4;
    float acc[4][4] = {};
#pragma unroll 4
    for (int k = 0; k < HID_F; ++k) {
        float4 b = *(const float4*)&Ws[k][tx * 4];
        float a0 = As[ty * 4 + 0][k];
        float a1 = As[ty * 4 + 1][k];
        float a2 = As[ty * 4 + 2][k];
        float a3 = As[ty * 4 + 3][k];
        acc[0][0] = fmaf(a0, b.x, acc[0][0]); acc[0][1] = fmaf(a0, b.y, acc[0][1]);
        acc[0][2] = fmaf(a0, b.z, acc[0][2]); acc[0][3] = fmaf(a0, b.w, acc[0][3]);
        acc[1][0] = fmaf(a1, b.x, acc[1][0]); acc[1][1] = fmaf(a1, b.y, acc[1][1]);
        acc[1][2] = fmaf(a1, b.z, acc[1][2]); acc[1][3] = fmaf(a1, b.w, acc[1][3]);
        acc[2][0] = fmaf(a2, b.x, acc[2][0]); acc[2][1] = fmaf(a2, b.y, acc[2][1]);
        acc[2][2] = fmaf(a2, b.z, acc[2][2]); acc[2][3] = fmaf(a2, b.w, acc[2][3]);
        acc[3][0] = fmaf(a3, b.x, acc[3][0]); acc[3][1] = fmaf(a3, b.y, acc[3][1]);
        acc[3][2] = fmaf(a3, b.z, acc[3][2]); acc[3][3] = fmaf(a3, b.w, acc[3][3]);
    }
#pragma unroll
    for (int j = 0; j < 4; ++j) {
        int row = r0 + ty * 4 + j;
        if (row < N_NODES) {
            float d = dis[row];
            float4 o;
            o.x = acc[j][0] * d; o.y = acc[j][1] * d;
            o.z = acc[j][2] * d; o.w = acc[j][3] * d;
            *(float4*)(hs2 + (size_t)row * OUT_F + tx * 4) = o;
        }
    }
}

// ---------------------------------------------------------------------------
// 8. gather conv2 + final epilogue (same 8-lane structure, no BN stats)
__global__ __launch_bounds__(256) void k_gather2(const int* __restrict__ rowptr,
                                                 const int* __restrict__ csr_src,
                                                 const float* __restrict__ hs,
                                                 const float* __restrict__ dis,
                                                 const float* __restrict__ b2,
                                                 float* __restrict__ out) {
    const int tid = threadIdx.x;
    const int g = tid >> 3;
    const int q = tid & 7;
    const int n = blockIdx.x * 16 + (g >> 1);
    const int cbase = (g & 1) * 8 + q;
    const float4* __restrict__ hs4 = (const float4*)hs;

    const int start = rowptr[n], end = rowptr[n + 1];
    float4 a0 = hs4[(size_t)n * 16 + cbase];
    float4 a1 = make_float4(0.f, 0.f, 0.f, 0.f);
    float4 a2 = make_float4(0.f, 0.f, 0.f, 0.f);
    float4 a3 = make_float4(0.f, 0.f, 0.f, 0.f);
    int i = start;
    for (; i + 3 < end; i += 4) {
        int s0 = csr_src[i + 0], s1 = csr_src[i + 1];
        int s2 = csr_src[i + 2], s3 = csr_src[i + 3];
        float4 v0 = hs4[(size_t)s0 * 16 + cbase];
        float4 v1 = hs4[(size_t)s1 * 16 + cbase];
        float4 v2 = hs4[(size_t)s2 * 16 + cbase];
        float4 v3 = hs4[(size_t)s3 * 16 + cbase];
        a0.x += v0.x; a0.y += v0.y; a0.z += v0.z; a0.w += v0.w;
        a1.x += v1.x; a1.y += v1.y; a1.z += v1.z; a1.w += v1.w;
        a2.x += v2.x; a2.y += v2.y; a2.z += v2.z; a2.w += v2.w;
        a3.x += v3.x; a3.y += v3.y; a3.z += v3.z; a3.w += v3.w;
    }
    for (; i < end; ++i) {
        int s0 = csr_src[i];
        float4 v0 = hs4[(size_t)s0 * 16 + cbase];
        a0.x += v0.x; a0.y += v0.y; a0.z += v0.z; a0.w += v0.w;
    }
    const float d = dis[n];
    const float4 bc = ((const float4*)b2)[cbase];
    float4 o;
    o.x = fmaf(d, a0.x + a1.x + a2.x + a3.x, bc.x);
    o.y = fmaf(d, a0.y + a1.y + a2.y + a3.y, bc.y);
    o.z = fmaf(d, a0.z + a1.z + a2.z + a3.z, bc.z);
    o.w = fmaf(d, a0.w + a1.w + a2.w + a3.w, bc.w);
    ((float4*)out)[(size_t)n * 16 + cbase] = o;
}

// ---------------------------------------------------------------------------
extern "C" void kernel_launch(void* const* d_in, const int* in_sizes, int n_in,
                              void* d_out, int out_size, void* d_ws, size_t ws_size,
                              hipStream_t stream) {
    const float* x   = (const float*)d_in[0];
    const int*   ei  = (const int*)d_in[1];
    const float* W1  = (const float*)d_in[2];
    const float* b1  = (const float*)d_in[3];
    const float* bnw = (const float*)d_in[4];
    const float* bnb = (const float*)d_in[5];
    const float* W2  = (const float*)d_in[6];
    const float* b2  = (const float*)d_in[7];
    float* out = (float*)d_out;

    // workspace layout (4-byte units, 16B-aligned segments):
    float* ws = (float*)d_ws;
    float* dis       = ws;                                 // 100352 floats
    int*   cnt_rp    = (int*)(ws + 100352);                // 100608 ints (cnt -> row_ptr)
    int*   cursor    = (int*)(ws + 100352 + 100608);       // 100352 ints
    int*   bsum      = (int*)(ws + 100352 + 100608 + 100352);        // 512 ints
    float* bnstats   = ws + 100352 + 100608 + 100352 + 512;          // 128 floats
    int*   csr_src   = (int*)(ws + 100352 + 100608 + 100352 + 512 + 128); // 1.6M ints
    float* bufA      = ws + 100352 + 100608 + 100352 + 512 + 128 + 1600000;   // N*64
    float* bufB      = bufA + (size_t)N_NODES * HID_F;                        // N*64
    // BN partials scratch lives in d_out (dead until k_gather2 rewrites it):
    float* partials  = out;   // NGBLK*128 floats <= out_size

    const int* srcv = ei;
    const int* dstv = ei + E_EDGES;

    hipMemsetAsync(cnt_rp, 0, (N_NODES + 1) * sizeof(int), stream);
    hipMemsetAsync(bnstats, 0, 128 * sizeof(float), stream);

    k_hist <<<(E_EDGES + 255) / 256, 256, 0, stream>>>(dstv, cnt_rp);
    k_dis  <<<NB_SCAN, 256, 0, stream>>>(cnt_rp, dis);
    k_scan1<<<NB_SCAN, 256, 0, stream>>>(cnt_rp, bsum);
    k_scan2<<<1, 512, 0, stream>>>(bsum, cnt_rp);
    k_scan3<<<NB_SCAN, 256, 0, stream>>>(cnt_rp, bsum, cursor);
    k_fill <<<(E_EDGES + 255) / 256, 256, 0, stream>>>(srcv, dstv, cursor, csr_src);

    k_gemm1<<<(N_NODES + 63) / 64, 256, 0, stream>>>(x, W1, dis, bufA);
    k_gather1<<<NGBLK, 256, 0, stream>>>(cnt_rp, csr_src, bufA, dis, b1, bufB, partials);
    k_bnfinal<<<64, 256, 0, stream>>>(partials, bnstats);
    k_gemm2<<<(N_NODES + 63) / 64, 256, 0, stream>>>(bufB, W2, dis, bnw, bnb, bnstats, bufA);
    k_gather2<<<NGBLK, 256, 0, stream>>>(cnt_rp, csr_src, bufA, dis, b2, out);
}

// Round 4
// 333.269 us; speedup vs baseline: 8.9983x; 1.4793x over previous
//
#include <hip/hip_runtime.h>

#define N_NODES 100000
#define E_EDGES 1600000
#define IN_F    128
#define HID_F   64
#define OUT_F   64
#define BN_EPS  1e-5f
#define NBUK    391    // ceil(N/256) coarse buckets (256 nodes each)
#define CHUNK   6250   // E / 256 blocks
#define NGBLK   6250   // N/16 gather blocks

// ---------------------------------------------------------------------------
// 1. coarse histogram: chist[dst>>8]++ via LDS aggregation
__global__ __launch_bounds__(512) void k_chist(const int* __restrict__ dstv,
                                               int* __restrict__ chist) {
    __shared__ int h[NBUK];
    const int tid = threadIdx.x;
    const int e0 = blockIdx.x * CHUNK;
    for (int b = tid; b < NBUK; b += 512) h[b] = 0;
    __syncthreads();
    for (int t = tid; t < CHUNK; t += 512)
        atomicAdd(&h[dstv[e0 + t] >> 8], 1);
    __syncthreads();
    for (int b = tid; b < NBUK; b += 512)
        if (h[b]) atomicAdd(&chist[b], h[b]);
}

// 2. exclusive scan of 391 coarse counts -> coff (in place) + working copy ccur
__global__ __launch_bounds__(512) void k_cscan(int* __restrict__ coff,
                                               int* __restrict__ ccur) {
    __shared__ int sh[512];
    const int tid = threadIdx.x;
    int v = (tid < NBUK) ? coff[tid] : 0;
    sh[tid] = v;
    __syncthreads();
    for (int off = 1; off < 512; off <<= 1) {
        int t = (tid >= off) ? sh[tid - off] : 0;
        __syncthreads();
        sh[tid] += t;
        __syncthreads();
    }
    int excl = sh[tid] - v;
    if (tid < NBUK) { coff[tid] = excl; ccur[tid] = excl; }
    if (tid == 0) coff[NBUK] = E_EDGES;
}

// 3. bucket scatter: aux[pos] = src<<8 | (dst&255), coarse-bucket-grouped.
//    Per-block LDS histogram reserves one contiguous run per bucket -> coalesced.
__global__ __launch_bounds__(512) void k_bucket(const int* __restrict__ srcv,
                                                const int* __restrict__ dstv,
                                                int* __restrict__ ccur,
                                                unsigned int* __restrict__ aux) {
    __shared__ int dl[CHUNK];                  // 25 KB
    __shared__ int hist[NBUK], base[NBUK], lcur[NBUK];
    const int tid = threadIdx.x;
    const int e0 = blockIdx.x * CHUNK;
    for (int b = tid; b < NBUK; b += 512) hist[b] = 0;
    __syncthreads();
    for (int t = tid; t < CHUNK; t += 512) {
        int d = dstv[e0 + t];
        dl[t] = d;
        atomicAdd(&hist[d >> 8], 1);
    }
    __syncthreads();
    for (int b = tid; b < NBUK; b += 512) {
        int h = hist[b];
        if (h) base[b] = atomicAdd(&ccur[b], h);
        lcur[b] = 0;
    }
    __syncthreads();
    for (int t = tid; t < CHUNK; t += 512) {
        int d = dl[t];
        int b = d >> 8;
        int off = atomicAdd(&lcur[b], 1);
        aux[base[b] + off] = ((unsigned int)srcv[e0 + t] << 8) | (unsigned int)(d & 255);
    }
}

// 4. per-bucket: per-node counts (LDS) -> rowptr + dis, then fine CSR placement.
//    All global writes land in the bucket's contiguous csr window.
__global__ __launch_bounds__(256) void k_csrnode(const int* __restrict__ coff,
                                                 const unsigned int* __restrict__ aux,
                                                 int* __restrict__ rowptr,
                                                 float* __restrict__ dis,
                                                 int* __restrict__ csr_src) {
    __shared__ int c0[256], sc[256], cur[256];
    const int tid = threadIdx.x;
    const int n0 = blockIdx.x * 256;
    const int nn = min(256, N_NODES - n0);
    const int estart = coff[blockIdx.x];
    const int eend   = coff[blockIdx.x + 1];
    c0[tid] = 0;
    __syncthreads();
    for (int e = estart + tid; e < eend; e += 256)
        atomicAdd(&c0[aux[e] & 255], 1);
    __syncthreads();
    int v = c0[tid];
    sc[tid] = v;
    __syncthreads();
    for (int off = 1; off < 256; off <<= 1) {
        int t = (tid >= off) ? sc[tid - off] : 0;
        __syncthreads();
        sc[tid] += t;
        __syncthreads();
    }
    int excl = sc[tid] - v;
    if (tid < nn) {
        int p = estart + excl;
        rowptr[n0 + tid] = p;
        cur[tid] = p;
        dis[n0 + tid] = rsqrtf((float)v + 1.0f);
    }
    if (blockIdx.x == NBUK - 1 && tid == 0) rowptr[N_NODES] = E_EDGES;
    __syncthreads();
    for (int e = estart + tid; e < eend; e += 256) {
        unsigned int u = aux[e];
        int pos = atomicAdd(&cur[u & 255], 1);
        csr_src[pos] = (int)(u >> 8);
    }
}

// ---------------------------------------------------------------------------
// 5. hs1 = dis * (x @ W1)
__global__ __launch_bounds__(256) void k_gemm1(const float* __restrict__ x,
                                               const float* __restrict__ W1,
                                               const float* __restrict__ dis,
                                               float* __restrict__ hs1) {
    __shared__ float Ws[IN_F][HID_F];
    __shared__ float As[64][68];
    const int tid = threadIdx.x;
    const int r0 = blockIdx.x * 64;

#pragma unroll
    for (int p = 0; p < 8; ++p) {
        int idx = p * 256 + tid;
        ((float4*)&Ws[0][0])[idx] = ((const float4*)W1)[idx];
    }

    const int tx = tid & 15, ty = tid >> 4;
    float acc[4][4] = {};

    for (int kk = 0; kk < IN_F; kk += 64) {
        __syncthreads();
#pragma unroll
        for (int p = 0; p < 4; ++p) {
            int idx = p * 256 + tid;
            int row = idx >> 4;
            int c4  = idx & 15;
            float4 v = make_float4(0.f, 0.f, 0.f, 0.f);
            if (r0 + row < N_NODES)
                v = ((const float4*)(x + (size_t)(r0 + row) * IN_F + kk))[c4];
            *(float4*)&As[row][c4 * 4] = v;
        }
        __syncthreads();
#pragma unroll 4
        for (int k2 = 0; k2 < 64; ++k2) {
            int k = kk + k2;
            float4 b = *(const float4*)&Ws[k][tx * 4];
            float a0 = As[ty * 4 + 0][k2];
            float a1 = As[ty * 4 + 1][k2];
            float a2 = As[ty * 4 + 2][k2];
            float a3 = As[ty * 4 + 3][k2];
            acc[0][0] = fmaf(a0, b.x, acc[0][0]); acc[0][1] = fmaf(a0, b.y, acc[0][1]);
            acc[0][2] = fmaf(a0, b.z, acc[0][2]); acc[0][3] = fmaf(a0, b.w, acc[0][3]);
            acc[1][0] = fmaf(a1, b.x, acc[1][0]); acc[1][1] = fmaf(a1, b.y, acc[1][1]);
            acc[1][2] = fmaf(a1, b.z, acc[1][2]); acc[1][3] = fmaf(a1, b.w, acc[1][3]);
            acc[2][0] = fmaf(a2, b.x, acc[2][0]); acc[2][1] = fmaf(a2, b.y, acc[2][1]);
            acc[2][2] = fmaf(a2, b.z, acc[2][2]); acc[2][3] = fmaf(a2, b.w, acc[2][3]);
            acc[3][0] = fmaf(a3, b.x, acc[3][0]); acc[3][1] = fmaf(a3, b.y, acc[3][1]);
            acc[3][2] = fmaf(a3, b.z, acc[3][2]); acc[3][3] = fmaf(a3, b.w, acc[3][3]);
        }
    }
#pragma unroll
    for (int j = 0; j < 4; ++j) {
        int row = r0 + ty * 4 + j;
        if (row < N_NODES) {
            float d = dis[row];
            float4 o;
            o.x = acc[j][0] * d; o.y = acc[j][1] * d;
            o.z = acc[j][2] * d; o.w = acc[j][3] * d;
            *(float4*)(hs1 + (size_t)row * HID_F + tx * 4) = o;
        }
    }
}

// ---------------------------------------------------------------------------
// 6. gather conv1 + epilogue; per-block BN partials (no atomics).
__global__ __launch_bounds__(256) void k_gather1(const int* __restrict__ rowptr,
                                                 const int* __restrict__ csr_src,
                                                 const float* __restrict__ hs,
                                                 const float* __restrict__ dis,
                                                 const float* __restrict__ b1,
                                                 float* __restrict__ agg,
                                                 float* __restrict__ partials) {
    const int tid = threadIdx.x;
    const int g = tid >> 3;
    const int q = tid & 7;
    const int n = blockIdx.x * 16 + (g >> 1);
    const int cbase = (g & 1) * 8 + q;          // float4 index within 64-col row
    const float4* __restrict__ hs4 = (const float4*)hs;

    const int start = rowptr[n], end = rowptr[n + 1];
    float4 a0 = hs4[(size_t)n * 16 + cbase];    // self term
    float4 a1 = make_float4(0.f, 0.f, 0.f, 0.f);
    float4 a2 = make_float4(0.f, 0.f, 0.f, 0.f);
    float4 a3 = make_float4(0.f, 0.f, 0.f, 0.f);
    int i = start;
    for (; i + 3 < end; i += 4) {
        int s0 = csr_src[i + 0], s1 = csr_src[i + 1];
        int s2 = csr_src[i + 2], s3 = csr_src[i + 3];
        float4 v0 = hs4[(size_t)s0 * 16 + cbase];
        float4 v1 = hs4[(size_t)s1 * 16 + cbase];
        float4 v2 = hs4[(size_t)s2 * 16 + cbase];
        float4 v3 = hs4[(size_t)s3 * 16 + cbase];
        a0.x += v0.x; a0.y += v0.y; a0.z += v0.z; a0.w += v0.w;
        a1.x += v1.x; a1.y += v1.y; a1.z += v1.z; a1.w += v1.w;
        a2.x += v2.x; a2.y += v2.y; a2.z += v2.z; a2.w += v2.w;
        a3.x += v3.x; a3.y += v3.y; a3.z += v3.z; a3.w += v3.w;
    }
    for (; i < end; ++i) {
        int s0 = csr_src[i];
        float4 v0 = hs4[(size_t)s0 * 16 + cbase];
        a0.x += v0.x; a0.y += v0.y; a0.z += v0.z; a0.w += v0.w;
    }
    const float d = dis[n];
    const float4 bc = ((const float4*)b1)[cbase];
    float4 o;
    o.x = fmaf(d, a0.x + a1.x + a2.x + a3.x, bc.x);
    o.y = fmaf(d, a0.y + a1.y + a2.y + a3.y, bc.y);
    o.z = fmaf(d, a0.z + a1.z + a2.z + a3.z, bc.z);
    o.w = fmaf(d, a0.w + a1.w + a2.w + a3.w, bc.w);
    ((float4*)agg)[(size_t)n * 16 + cbase] = o;

    __shared__ float4 red[256];
    red[tid] = o;
    __syncthreads();
    for (int s = 128; s >= 16; s >>= 1) {
        if (tid < s) {
            red[tid].x += red[tid + s].x; red[tid].y += red[tid + s].y;
            red[tid].z += red[tid + s].z; red[tid].w += red[tid + s].w;
        }
        __syncthreads();
    }
    float4* pr = (float4*)(partials + (size_t)blockIdx.x * 128);
    if (tid < 16) pr[tid] = red[tid];           // sums: floats [0..63]
    __syncthreads();
    float4 sq = make_float4(o.x * o.x, o.y * o.y, o.z * o.z, o.w * o.w);
    red[tid] = sq;
    __syncthreads();
    for (int s = 128; s >= 16; s >>= 1) {
        if (tid < s) {
            red[tid].x += red[tid + s].x; red[tid].y += red[tid + s].y;
            red[tid].z += red[tid + s].z; red[tid].w += red[tid + s].w;
        }
        __syncthreads();
    }
    if (tid < 16) pr[16 + tid] = red[tid];      // sumsq: floats [64..127]
}

// 6b. reduce partials[NGBLK][128] -> bnstats[128]
__global__ __launch_bounds__(256) void k_bnfinal(const float* __restrict__ partials,
                                                 float* __restrict__ bnstats) {
    const int tid = threadIdx.x;
    const int col = tid & 127;
    const int half = tid >> 7;
    float s = 0.f;
    for (int r = blockIdx.x * 2 + half; r < NGBLK; r += 128)
        s += partials[(size_t)r * 128 + col];
    __shared__ float sh[256];
    sh[tid] = s;
    __syncthreads();
    if (tid < 128) unsafeAtomicAdd(&bnstats[col], sh[tid] + sh[tid + 128]);
}

// ---------------------------------------------------------------------------
// 7. hs2 = dis * (relu(BN(agg1)) @ W2)
__global__ __launch_bounds__(256) void k_gemm2(const float* __restrict__ agg1,
                                               const float* __restrict__ W2,
                                               const float* __restrict__ dis,
                                               const float* __restrict__ bnw,
                                               const float* __restrict__ bnb,
                                               const float* __restrict__ bnstats,
                                               float* __restrict__ hs2) {
    __shared__ float Ws[HID_F][OUT_F];
    __shared__ float As[64][68];
    __shared__ float scale_s[64], shift_s[64];
    const int tid = threadIdx.x;
    const int r0 = blockIdx.x * 64;

    if (tid < 64) {
        const float invN = 1.0f / (float)N_NODES;
        float mean = bnstats[tid] * invN;
        float var  = bnstats[64 + tid] * invN - mean * mean;
        float sc   = bnw[tid] * rsqrtf(var + BN_EPS);
        scale_s[tid] = sc;
        shift_s[tid] = fmaf(-mean, sc, bnb[tid]);
    }
#pragma unroll
    for (int p = 0; p < 4; ++p) {
        int idx = p * 256 + tid;
        ((float4*)&Ws[0][0])[idx] = ((const float4*)W2)[idx];
    }
    __syncthreads();
#pragma unroll
    for (int p = 0; p < 4; ++p) {
        int idx = p * 256 + tid;
        int row = idx >> 4;
        int c4  = idx & 15;
        float4 v = make_float4(0.f, 0.f, 0.f, 0.f);
        if (r0 + row < N_NODES) {
            v = ((const float4*)(agg1 + (size_t)(r0 + row) * HID_F))[c4];
            int k0 = c4 * 4;
            v.x = fmaxf(fmaf(v.x, scale_s[k0 + 0], shift_s[k0 + 0]), 0.f);
            v.y = fmaxf(fmaf(v.y, scale_s[k0 + 1], shift_s[k0 + 1]), 0.f);
            v.z = fmaxf(fmaf(v.z, scale_s[k0 + 2], shift_s[k0 + 2]), 0.f);
            v.w = fmaxf(fmaf(v.w, scale_s[k0 + 3], shift_s[k0 + 3]), 0.f);
        }
        *(float4*)&As[row][c4 * 4] = v;
    }
    __syncthreads();
    const int tx = tid & 15, ty = tid >> 4;
    float acc[4][4] = {};
#pragma unroll 4
    for (int k = 0; k < HID_F; ++k) {
        float4 b = *(const float4*)&Ws[k][tx * 4];
        float a0 = As[ty * 4 + 0][k];
        float a1 = As[ty * 4 + 1][k];
        float a2 = As[ty * 4 + 2][k];
        float a3 = As[ty * 4 + 3][k];
        acc[0][0] = fmaf(a0, b.x, acc[0][0]); acc[0][1] = fmaf(a0, b.y, acc[0][1]);
        acc[0][2] = fmaf(a0, b.z, acc[0][2]); acc[0][3] = fmaf(a0, b.w, acc[0][3]);
        acc[1][0] = fmaf(a1, b.x, acc[1][0]); acc[1][1] = fmaf(a1, b.y, acc[1][1]);
        acc[1][2] = fmaf(a1, b.z, acc[1][2]); acc[1][3] = fmaf(a1, b.w, acc[1][3]);
        acc[2][0] = fmaf(a2, b.x, acc[2][0]); acc[2][1] = fmaf(a2, b.y, acc[2][1]);
        acc[2][2] = fmaf(a2, b.z, acc[2][2]); acc[2][3] = fmaf(a2, b.w, acc[2][3]);
        acc[3][0] = fmaf(a3, b.x, acc[3][0]); acc[3][1] = fmaf(a3, b.y, acc[3][1]);
        acc[3][2] = fmaf(a3, b.z, acc[3][2]); acc[3][3] = fmaf(a3, b.w, acc[3][3]);
    }
#pragma unroll
    for (int j = 0; j < 4; ++j) {
        int row = r0 + ty * 4 + j;
        if (row < N_NODES) {
            float d = dis[row];
            float4 o;
            o.x = acc[j][0] * d; o.y = acc[j][1] * d;
            o.z = acc[j][2] * d; o.w = acc[j][3] * d;
            *(float4*)(hs2 + (size_t)row * OUT_F + tx * 4) = o;
        }
    }
}

// ---------------------------------------------------------------------------
// 8. gather conv2 + final epilogue
__global__ __launch_bounds__(256) void k_gather2(const int* __restrict__ rowptr,
                                                 const int* __restrict__ csr_src,
                                                 const float* __restrict__ hs,
                                                 const float* __restrict__ dis,
                                                 const float* __restrict__ b2,
                                                 float* __restrict__ out) {
    const int tid = threadIdx.x;
    const int g = tid >> 3;
    const int q = tid & 7;
    const int n = blockIdx.x * 16 + (g >> 1);
    const int cbase = (g & 1) * 8 + q;
    const float4* __restrict__ hs4 = (const float4*)hs;

    const int start = rowptr[n], end = rowptr[n + 1];
    float4 a0 = hs4[(size_t)n * 16 + cbase];
    float4 a1 = make_float4(0.f, 0.f, 0.f, 0.f);
    float4 a2 = make_float4(0.f, 0.f, 0.f, 0.f);
    float4 a3 = make_float4(0.f, 0.f, 0.f, 0.f);
    int i = start;
    for (; i + 3 < end; i += 4) {
        int s0 = csr_src[i + 0], s1 = csr_src[i + 1];
        int s2 = csr_src[i + 2], s3 = csr_src[i + 3];
        float4 v0 = hs4[(size_t)s0 * 16 + cbase];
        float4 v1 = hs4[(size_t)s1 * 16 + cbase];
        float4 v2 = hs4[(size_t)s2 * 16 + cbase];
        float4 v3 = hs4[(size_t)s3 * 16 + cbase];
        a0.x += v0.x; a0.y += v0.y; a0.z += v0.z; a0.w += v0.w;
        a1.x += v1.x; a1.y += v1.y; a1.z += v1.z; a1.w += v1.w;
        a2.x += v2.x; a2.y += v2.y; a2.z += v2.z; a2.w += v2.w;
        a3.x += v3.x; a3.y += v3.y; a3.z += v3.z; a3.w += v3.w;
    }
    for (; i < end; ++i) {
        int s0 = csr_src[i];
        float4 v0 = hs4[(size_t)s0 * 16 + cbase];
        a0.x += v0.x; a0.y += v0.y; a0.z += v0.z; a0.w += v0.w;
    }
    const float d = dis[n];
    const float4 bc = ((const float4*)b2)[cbase];
    float4 o;
    o.x = fmaf(d, a0.x + a1.x + a2.x + a3.x, bc.x);
    o.y = fmaf(d, a0.y + a1.y + a2.y + a3.y, bc.y);
    o.z = fmaf(d, a0.z + a1.z + a2.z + a3.z, bc.z);
    o.w = fmaf(d, a0.w + a1.w + a2.w + a3.w, bc.w);
    ((float4*)out)[(size_t)n * 16 + cbase] = o;
}

// ---------------------------------------------------------------------------
extern "C" void kernel_launch(void* const* d_in, const int* in_sizes, int n_in,
                              void* d_out, int out_size, void* d_ws, size_t ws_size,
                              hipStream_t stream) {
    const float* x   = (const float*)d_in[0];
    const int*   ei  = (const int*)d_in[1];
    const float* W1  = (const float*)d_in[2];
    const float* b1  = (const float*)d_in[3];
    const float* bnw = (const float*)d_in[4];
    const float* bnb = (const float*)d_in[5];
    const float* W2  = (const float*)d_in[6];
    const float* b2  = (const float*)d_in[7];
    float* out = (float*)d_out;

    // workspace layout (floats, 16B-aligned segments):
    float* ws = (float*)d_ws;
    float*        dis     = ws;                               // 100352
    int*          rowptr  = (int*)(ws + 100352);              // 100608 (N+1 used)
    int*          coff    = (int*)(ws + 100352 + 100608);     // 512 (NBUK+1 used)
    int*          ccur    = (int*)(ws + 100352 + 100608 + 512);          // 512
    float*        bnstats = ws + 100352 + 100608 + 512 + 512;            // 128
    int*          csr_src = (int*)(ws + 100352 + 100608 + 512 + 512 + 128); // 1.6M
    float*        bufA    = ws + 100352 + 100608 + 512 + 512 + 128 + 1600000; // N*64
    float*        bufB    = bufA + (size_t)N_NODES * HID_F;                   // N*64
    unsigned int* aux     = (unsigned int*)bufA;  // aliases bufA; dead before gemm1
    float*        partials = out;                 // NGBLK*128 floats, dead until gather2

    const int* srcv = ei;
    const int* dstv = ei + E_EDGES;

    hipMemsetAsync(coff, 0, (NBUK + 1) * sizeof(int), stream);
    hipMemsetAsync(bnstats, 0, 128 * sizeof(float), stream);

    k_chist  <<<256, 512, 0, stream>>>(dstv, coff);
    k_cscan  <<<1, 512, 0, stream>>>(coff, ccur);
    k_bucket <<<256, 512, 0, stream>>>(srcv, dstv, ccur, aux);
    k_csrnode<<<NBUK, 256, 0, stream>>>(coff, aux, rowptr, dis, csr_src);

    k_gemm1  <<<(N_NODES + 63) / 64, 256, 0, stream>>>(x, W1, dis, bufA);
    k_gather1<<<NGBLK, 256, 0, stream>>>(rowptr, csr_src, bufA, dis, b1, bufB, partials);
    k_bnfinal<<<64, 256, 0, stream>>>(partials, bnstats);
    k_gemm2  <<<(N_NODES + 63) / 64, 256, 0, stream>>>(bufB, W2, dis, bnw, bnb, bnstats, bufA);
    k_gather2<<<NGBLK, 256, 0, stream>>>(rowptr, csr_src, bufA, dis, b2, out);
}

// Round 5
// 275.709 us; speedup vs baseline: 10.8769x; 1.2088x over previous
//
#include <hip/hip_runtime.h>

#define N_NODES 100000
#define E_EDGES 1600000
#define IN_F    128
#define HID_F   64
#define OUT_F   64
#define BN_EPS  1e-5f
#define NBUK    391    // ceil(N/256) coarse buckets (256 nodes each)
#define CHUNK   6250   // E / 256 blocks
#define NGBLK   3125   // N/32 gather blocks (32 nodes per block, 8 lanes/node)

// bf16 helpers ---------------------------------------------------------------
__device__ __forceinline__ float bflo(unsigned int u) { return __uint_as_float(u << 16); }
__device__ __forceinline__ float bfhi(unsigned int u) { return __uint_as_float(u & 0xFFFF0000u); }
__device__ __forceinline__ unsigned int pack2bf(float a, float b) {
    unsigned int ua = __float_as_uint(a), ub = __float_as_uint(b);
    ua = (ua + 0x7fffu + ((ua >> 16) & 1u)) >> 16;          // RNE
    ub = (ub + 0x7fffu + ((ub >> 16) & 1u)) >> 16;
    return ua | (ub << 16);
}
#define ADD8(A, u)                                           \
    do {                                                     \
        A[0] += bflo((u).x); A[1] += bfhi((u).x);            \
        A[2] += bflo((u).y); A[3] += bfhi((u).y);            \
        A[4] += bflo((u).z); A[5] += bfhi((u).z);            \
        A[6] += bflo((u).w); A[7] += bfhi((u).w);            \
    } while (0)

// ---------------------------------------------------------------------------
// 1. coarse histogram: chist[dst>>8]++ via LDS aggregation
__global__ __launch_bounds__(512) void k_chist(const int* __restrict__ dstv,
                                               int* __restrict__ chist) {
    __shared__ int h[NBUK];
    const int tid = threadIdx.x;
    const int e0 = blockIdx.x * CHUNK;
    for (int b = tid; b < NBUK; b += 512) h[b] = 0;
    __syncthreads();
    for (int t = tid; t < CHUNK; t += 512)
        atomicAdd(&h[dstv[e0 + t] >> 8], 1);
    __syncthreads();
    for (int b = tid; b < NBUK; b += 512)
        if (h[b]) atomicAdd(&chist[b], h[b]);
}

// 2. exclusive scan of 391 coarse counts -> coff (in place) + working copy ccur
__global__ __launch_bounds__(512) void k_cscan(int* __restrict__ coff,
                                               int* __restrict__ ccur) {
    __shared__ int sh[512];
    const int tid = threadIdx.x;
    int v = (tid < NBUK) ? coff[tid] : 0;
    sh[tid] = v;
    __syncthreads();
    for (int off = 1; off < 512; off <<= 1) {
        int t = (tid >= off) ? sh[tid - off] : 0;
        __syncthreads();
        sh[tid] += t;
        __syncthreads();
    }
    int excl = sh[tid] - v;
    if (tid < NBUK) { coff[tid] = excl; ccur[tid] = excl; }
    if (tid == 0) coff[NBUK] = E_EDGES;
}

// 3. bucket scatter: aux[pos] = src<<8 | (dst&255), coarse-bucket-grouped.
__global__ __launch_bounds__(512) void k_bucket(const int* __restrict__ srcv,
                                                const int* __restrict__ dstv,
                                                int* __restrict__ ccur,
                                                unsigned int* __restrict__ aux) {
    __shared__ int dl[CHUNK];                  // 25 KB
    __shared__ int hist[NBUK], base[NBUK], lcur[NBUK];
    const int tid = threadIdx.x;
    const int e0 = blockIdx.x * CHUNK;
    for (int b = tid; b < NBUK; b += 512) hist[b] = 0;
    __syncthreads();
    for (int t = tid; t < CHUNK; t += 512) {
        int d = dstv[e0 + t];
        dl[t] = d;
        atomicAdd(&hist[d >> 8], 1);
    }
    __syncthreads();
    for (int b = tid; b < NBUK; b += 512) {
        int h = hist[b];
        if (h) base[b] = atomicAdd(&ccur[b], h);
        lcur[b] = 0;
    }
    __syncthreads();
    for (int t = tid; t < CHUNK; t += 512) {
        int d = dl[t];
        int b = d >> 8;
        int off = atomicAdd(&lcur[b], 1);
        aux[base[b] + off] = ((unsigned int)srcv[e0 + t] << 8) | (unsigned int)(d & 255);
    }
}

// 4. per-bucket: per-node counts (LDS) -> rowptr + dis, then fine CSR placement.
__global__ __launch_bounds__(256) void k_csrnode(const int* __restrict__ coff,
                                                 const unsigned int* __restrict__ aux,
                                                 int* __restrict__ rowptr,
                                                 float* __restrict__ dis,
                                                 int* __restrict__ csr_src) {
    __shared__ int c0[256], sc[256], cur[256];
    const int tid = threadIdx.x;
    const int n0 = blockIdx.x * 256;
    const int nn = min(256, N_NODES - n0);
    const int estart = coff[blockIdx.x];
    const int eend   = coff[blockIdx.x + 1];
    c0[tid] = 0;
    __syncthreads();
    for (int e = estart + tid; e < eend; e += 256)
        atomicAdd(&c0[aux[e] & 255], 1);
    __syncthreads();
    int v = c0[tid];
    sc[tid] = v;
    __syncthreads();
    for (int off = 1; off < 256; off <<= 1) {
        int t = (tid >= off) ? sc[tid - off] : 0;
        __syncthreads();
        sc[tid] += t;
        __syncthreads();
    }
    int excl = sc[tid] - v;
    if (tid < nn) {
        int p = estart + excl;
        rowptr[n0 + tid] = p;
        cur[tid] = p;
        dis[n0 + tid] = rsqrtf((float)v + 1.0f);
    }
    if (blockIdx.x == NBUK - 1 && tid == 0) rowptr[N_NODES] = E_EDGES;
    __syncthreads();
    for (int e = estart + tid; e < eend; e += 256) {
        unsigned int u = aux[e];
        int pos = atomicAdd(&cur[u & 255], 1);
        csr_src[pos] = (int)(u >> 8);
    }
}

// ---------------------------------------------------------------------------
// 5. hs1 = bf16( dis * (x @ W1) )
__global__ __launch_bounds__(256) void k_gemm1(const float* __restrict__ x,
                                               const float* __restrict__ W1,
                                               const float* __restrict__ dis,
                                               unsigned short* __restrict__ hs1) {
    __shared__ float Ws[IN_F][HID_F];
    __shared__ float As[64][68];
    const int tid = threadIdx.x;
    const int r0 = blockIdx.x * 64;

#pragma unroll
    for (int p = 0; p < 8; ++p) {
        int idx = p * 256 + tid;
        ((float4*)&Ws[0][0])[idx] = ((const float4*)W1)[idx];
    }

    const int tx = tid & 15, ty = tid >> 4;
    float acc[4][4] = {};

    for (int kk = 0; kk < IN_F; kk += 64) {
        __syncthreads();
#pragma unroll
        for (int p = 0; p < 4; ++p) {
            int idx = p * 256 + tid;
            int row = idx >> 4;
            int c4  = idx & 15;
            float4 v = make_float4(0.f, 0.f, 0.f, 0.f);
            if (r0 + row < N_NODES)
                v = ((const float4*)(x + (size_t)(r0 + row) * IN_F + kk))[c4];
            *(float4*)&As[row][c4 * 4] = v;
        }
        __syncthreads();
#pragma unroll 4
        for (int k2 = 0; k2 < 64; ++k2) {
            int k = kk + k2;
            float4 b = *(const float4*)&Ws[k][tx * 4];
            float a0 = As[ty * 4 + 0][k2];
            float a1 = As[ty * 4 + 1][k2];
            float a2 = As[ty * 4 + 2][k2];
            float a3 = As[ty * 4 + 3][k2];
            acc[0][0] = fmaf(a0, b.x, acc[0][0]); acc[0][1] = fmaf(a0, b.y, acc[0][1]);
            acc[0][2] = fmaf(a0, b.z, acc[0][2]); acc[0][3] = fmaf(a0, b.w, acc[0][3]);
            acc[1][0] = fmaf(a1, b.x, acc[1][0]); acc[1][1] = fmaf(a1, b.y, acc[1][1]);
            acc[1][2] = fmaf(a1, b.z, acc[1][2]); acc[1][3] = fmaf(a1, b.w, acc[1][3]);
            acc[2][0] = fmaf(a2, b.x, acc[2][0]); acc[2][1] = fmaf(a2, b.y, acc[2][1]);
            acc[2][2] = fmaf(a2, b.z, acc[2][2]); acc[2][3] = fmaf(a2, b.w, acc[2][3]);
            acc[3][0] = fmaf(a3, b.x, acc[3][0]); acc[3][1] = fmaf(a3, b.y, acc[3][1]);
            acc[3][2] = fmaf(a3, b.z, acc[3][2]); acc[3][3] = fmaf(a3, b.w, acc[3][3]);
        }
    }
#pragma unroll
    for (int j = 0; j < 4; ++j) {
        int row = r0 + ty * 4 + j;
        if (row < N_NODES) {
            float d = dis[row];
            uint2 o;
            o.x = pack2bf(acc[j][0] * d, acc[j][1] * d);
            o.y = pack2bf(acc[j][2] * d, acc[j][3] * d);
            *(uint2*)&hs1[(size_t)row * HID_F + tx * 4] = o;
        }
    }
}

// ---------------------------------------------------------------------------
// 6. gather conv1 (bf16 rows) + epilogue + per-block BN partials.
//    8 lanes per node read one full 128B row as uint4; 32 nodes/block.
__global__ __launch_bounds__(256) void k_gather1(const int* __restrict__ rowptr,
                                                 const int* __restrict__ csr_src,
                                                 const unsigned short* __restrict__ hsb,
                                                 const float* __restrict__ dis,
                                                 const float* __restrict__ b1,
                                                 float* __restrict__ agg,
                                                 float* __restrict__ partials) {
    const int tid = threadIdx.x;
    const int g = tid >> 3, q = tid & 7;
    const int n = blockIdx.x * 32 + g;
    const uint4* __restrict__ hs16 = (const uint4*)hsb;   // row = 8 uint4

    const int start = rowptr[n], end = rowptr[n + 1];
    float A0[8] = {}, A1[8] = {}, A2[8] = {}, A3[8] = {};
    {   // self term
        uint4 u = hs16[(size_t)n * 8 + q];
        ADD8(A0, u);
    }
    int i = start;
    for (; i + 3 < end; i += 4) {
        int s0 = csr_src[i + 0], s1 = csr_src[i + 1];
        int s2 = csr_src[i + 2], s3 = csr_src[i + 3];
        uint4 u0 = hs16[(size_t)s0 * 8 + q];
        uint4 u1 = hs16[(size_t)s1 * 8 + q];
        uint4 u2 = hs16[(size_t)s2 * 8 + q];
        uint4 u3 = hs16[(size_t)s3 * 8 + q];
        ADD8(A0, u0); ADD8(A1, u1); ADD8(A2, u2); ADD8(A3, u3);
    }
    for (; i < end; ++i) {
        uint4 u = hs16[(size_t)csr_src[i] * 8 + q];
        ADD8(A0, u);
    }
    const float d = dis[n];
    const float4 blo = ((const float4*)b1)[q * 2];
    const float4 bhi = ((const float4*)b1)[q * 2 + 1];
    float o[8];
    o[0] = fmaf(d, A0[0] + A1[0] + A2[0] + A3[0], blo.x);
    o[1] = fmaf(d, A0[1] + A1[1] + A2[1] + A3[1], blo.y);
    o[2] = fmaf(d, A0[2] + A1[2] + A2[2] + A3[2], blo.z);
    o[3] = fmaf(d, A0[3] + A1[3] + A2[3] + A3[3], blo.w);
    o[4] = fmaf(d, A0[4] + A1[4] + A2[4] + A3[4], bhi.x);
    o[5] = fmaf(d, A0[5] + A1[5] + A2[5] + A3[5], bhi.y);
    o[6] = fmaf(d, A0[6] + A1[6] + A2[6] + A3[6], bhi.z);
    o[7] = fmaf(d, A0[7] + A1[7] + A2[7] + A3[7], bhi.w);
    float4* ag = (float4*)(agg + (size_t)n * HID_F + q * 8);
    ag[0] = make_float4(o[0], o[1], o[2], o[3]);
    ag[1] = make_float4(o[4], o[5], o[6], o[7]);

    // --- BN partials: per-column sums over the 32 nodes of this block.
    __shared__ float4 redA[256], redB[256];   // 8 KB
    redA[tid] = make_float4(o[0], o[1], o[2], o[3]);
    redB[tid] = make_float4(o[4], o[5], o[6], o[7]);
    __syncthreads();
    for (int s = 128; s >= 8; s >>= 1) {
        if (tid < s) {
            redA[tid].x += redA[tid + s].x; redA[tid].y += redA[tid + s].y;
            redA[tid].z += redA[tid + s].z; redA[tid].w += redA[tid + s].w;
            redB[tid].x += redB[tid + s].x; redB[tid].y += redB[tid + s].y;
            redB[tid].z += redB[tid + s].z; redB[tid].w += redB[tid + s].w;
        }
        __syncthreads();
    }
    float4* pr = (float4*)(partials + (size_t)blockIdx.x * 128);
    if (tid < 8) { pr[tid * 2] = redA[tid]; pr[tid * 2 + 1] = redB[tid]; }
    __syncthreads();
    redA[tid] = make_float4(o[0] * o[0], o[1] * o[1], o[2] * o[2], o[3] * o[3]);
    redB[tid] = make_float4(o[4] * o[4], o[5] * o[5], o[6] * o[6], o[7] * o[7]);
    __syncthreads();
    for (int s = 128; s >= 8; s >>= 1) {
        if (tid < s) {
            redA[tid].x += redA[tid + s].x; redA[tid].y += redA[tid + s].y;
            redA[tid].z += redA[tid + s].z; redA[tid].w += redA[tid + s].w;
            redB[tid].x += redB[tid + s].x; redB[tid].y += redB[tid + s].y;
            redB[tid].z += redB[tid + s].z; redB[tid].w += redB[tid + s].w;
        }
        __syncthreads();
    }
    if (tid < 8) { pr[16 + tid * 2] = redA[tid]; pr[16 + tid * 2 + 1] = redB[tid]; }
}

// 6b. reduce partials[NGBLK][128] -> bnstats[128]
__global__ __launch_bounds__(256) void k_bnfinal(const float* __restrict__ partials,
                                                 float* __restrict__ bnstats) {
    const int tid = threadIdx.x;
    const int col = tid & 127;
    const int half = tid >> 7;
    float s = 0.f;
    for (int r = blockIdx.x * 2 + half; r < NGBLK; r += 128)
        s += partials[(size_t)r * 128 + col];
    __shared__ float sh[256];
    sh[tid] = s;
    __syncthreads();
    if (tid < 128) unsafeAtomicAdd(&bnstats[col], sh[tid] + sh[tid + 128]);
}

// ---------------------------------------------------------------------------
// 7. hs2 = bf16( dis * (relu(BN(agg1)) @ W2) )
__global__ __launch_bounds__(256) void k_gemm2(const float* __restrict__ agg1,
                                               const float* __restrict__ W2,
                                               const float* __restrict__ dis,
                                               const float* __restrict__ bnw,
                                               const float* __restrict__ bnb,
                                               const float* __restrict__ bnstats,
                                               unsigned short* __restrict__ hs2) {
    __shared__ float Ws[HID_F][OUT_F];
    __shared__ float As[64][68];
    __shared__ float scale_s[64], shift_s[64];
    const int tid = threadIdx.x;
    const int r0 = blockIdx.x * 64;

    if (tid < 64) {
        const float invN = 1.0f / (float)N_NODES;
        float mean = bnstats[tid] * invN;
        float var  = bnstats[64 + tid] * invN - mean * mean;
        float sc   = bnw[tid] * rsqrtf(var + BN_EPS);
        scale_s[tid] = sc;
        shift_s[tid] = fmaf(-mean, sc, bnb[tid]);
    }
#pragma unroll
    for (int p = 0; p < 4; ++p) {
        int idx = p * 256 + tid;
        ((float4*)&Ws[0][0])[idx] = ((const float4*)W2)[idx];
    }
    __syncthreads();
#pragma unroll
    for (int p = 0; p < 4; ++p) {
        int idx = p * 256 + tid;
        int row = idx >> 4;
        int c4  = idx & 15;
        float4 v = make_float4(0.f, 0.f, 0.f, 0.f);
        if (r0 + row < N_NODES) {
            v = ((const float4*)(agg1 + (size_t)(r0 + row) * HID_F))[c4];
            int k0 = c4 * 4;
            v.x = fmaxf(fmaf(v.x, scale_s[k0 + 0], shift_s[k0 + 0]), 0.f);
            v.y = fmaxf(fmaf(v.y, scale_s[k0 + 1], shift_s[k0 + 1]), 0.f);
            v.z = fmaxf(fmaf(v.z, scale_s[k0 + 2], shift_s[k0 + 2]), 0.f);
            v.w = fmaxf(fmaf(v.w, scale_s[k0 + 3], shift_s[k0 + 3]), 0.f);
        }
        *(float4*)&As[row][c4 * 4] = v;
    }
    __syncthreads();
    const int tx = tid & 15, ty = tid >> 4;
    float acc[4][4] = {};
#pragma unroll 4
    for (int k = 0; k < HID_F; ++k) {
        float4 b = *(const float4*)&Ws[k][tx * 4];
        float a0 = As[ty * 4 + 0][k];
        float a1 = As[ty * 4 + 1][k];
        float a2 = As[ty * 4 + 2][k];
        float a3 = As[ty * 4 + 3][k];
        acc[0][0] = fmaf(a0, b.x, acc[0][0]); acc[0][1] = fmaf(a0, b.y, acc[0][1]);
        acc[0][2] = fmaf(a0, b.z, acc[0][2]); acc[0][3] = fmaf(a0, b.w, acc[0][3]);
        acc[1][0] = fmaf(a1, b.x, acc[1][0]); acc[1][1] = fmaf(a1, b.y, acc[1][1]);
        acc[1][2] = fmaf(a1, b.z, acc[1][2]); acc[1][3] = fmaf(a1, b.w, acc[1][3]);
        acc[2][0] = fmaf(a2, b.x, acc[2][0]); acc[2][1] = fmaf(a2, b.y, acc[2][1]);
        acc[2][2] = fmaf(a2, b.z, acc[2][2]); acc[2][3] = fmaf(a2, b.w, acc[2][3]);
        acc[3][0] = fmaf(a3, b.x, acc[3][0]); acc[3][1] = fmaf(a3, b.y, acc[3][1]);
        acc[3][2] = fmaf(a3, b.z, acc[3][2]); acc[3][3] = fmaf(a3, b.w, acc[3][3]);
    }
#pragma unroll
    for (int j = 0; j < 4; ++j) {
        int row = r0 + ty * 4 + j;
        if (row < N_NODES) {
            float d = dis[row];
            uint2 o;
            o.x = pack2bf(acc[j][0] * d, acc[j][1] * d);
            o.y = pack2bf(acc[j][2] * d, acc[j][3] * d);
            *(uint2*)&hs2[(size_t)row * OUT_F + tx * 4] = o;
        }
    }
}

// ---------------------------------------------------------------------------
// 8. gather conv2 (bf16 rows) + final epilogue -> fp32 out
__global__ __launch_bounds__(256) void k_gather2(const int* __restrict__ rowptr,
                                                 const int* __restrict__ csr_src,
                                                 const unsigned short* __restrict__ hsb,
                                                 const float* __restrict__ dis,
                                                 const float* __restrict__ b2,
                                                 float* __restrict__ out) {
    const int tid = threadIdx.x;
    const int g = tid >> 3, q = tid & 7;
    const int n = blockIdx.x * 32 + g;
    const uint4* __restrict__ hs16 = (const uint4*)hsb;

    const int start = rowptr[n], end = rowptr[n + 1];
    float A0[8] = {}, A1[8] = {}, A2[8] = {}, A3[8] = {};
    {
        uint4 u = hs16[(size_t)n * 8 + q];
        ADD8(A0, u);
    }
    int i = start;
    for (; i + 3 < end; i += 4) {
        int s0 = csr_src[i + 0], s1 = csr_src[i + 1];
        int s2 = csr_src[i + 2], s3 = csr_src[i + 3];
        uint4 u0 = hs16[(size_t)s0 * 8 + q];
        uint4 u1 = hs16[(size_t)s1 * 8 + q];
        uint4 u2 = hs16[(size_t)s2 * 8 + q];
        uint4 u3 = hs16[(size_t)s3 * 8 + q];
        ADD8(A0, u0); ADD8(A1, u1); ADD8(A2, u2); ADD8(A3, u3);
    }
    for (; i < end; ++i) {
        uint4 u = hs16[(size_t)csr_src[i] * 8 + q];
        ADD8(A0, u);
    }
    const float d = dis[n];
    const float4 blo = ((const float4*)b2)[q * 2];
    const float4 bhi = ((const float4*)b2)[q * 2 + 1];
    float4 o0, o1;
    o0.x = fmaf(d, A0[0] + A1[0] + A2[0] + A3[0], blo.x);
    o0.y = fmaf(d, A0[1] + A1[1] + A2[1] + A3[1], blo.y);
    o0.z = fmaf(d, A0[2] + A1[2] + A2[2] + A3[2], blo.z);
    o0.w = fmaf(d, A0[3] + A1[3] + A2[3] + A3[3], blo.w);
    o1.x = fmaf(d, A0[4] + A1[4] + A2[4] + A3[4], bhi.x);
    o1.y = fmaf(d, A0[5] + A1[5] + A2[5] + A3[5], bhi.y);
    o1.z = fmaf(d, A0[6] + A1[6] + A2[6] + A3[6], bhi.z);
    o1.w = fmaf(d, A0[7] + A1[7] + A2[7] + A3[7], bhi.w);
    float4* op = (float4*)(out + (size_t)n * OUT_F + q * 8);
    op[0] = o0;
    op[1] = o1;
}

// ---------------------------------------------------------------------------
extern "C" void kernel_launch(void* const* d_in, const int* in_sizes, int n_in,
                              void* d_out, int out_size, void* d_ws, size_t ws_size,
                              hipStream_t stream) {
    const float* x   = (const float*)d_in[0];
    const int*   ei  = (const int*)d_in[1];
    const float* W1  = (const float*)d_in[2];
    const float* b1  = (const float*)d_in[3];
    const float* bnw = (const float*)d_in[4];
    const float* bnb = (const float*)d_in[5];
    const float* W2  = (const float*)d_in[6];
    const float* b2  = (const float*)d_in[7];
    float* out = (float*)d_out;

    // workspace layout (floats, 16B-aligned segments):
    float* ws = (float*)d_ws;
    float*        dis     = ws;                               // 100352
    int*          rowptr  = (int*)(ws + 100352);              // 100608 (N+1 used)
    int*          coff    = (int*)(ws + 100352 + 100608);     // 512 (NBUK+1 used)
    int*          ccur    = (int*)(ws + 100352 + 100608 + 512);          // 512
    float*        bnstats = ws + 100352 + 100608 + 512 + 512;            // 128
    int*          csr_src = (int*)(ws + 100352 + 100608 + 512 + 512 + 128); // 1.6M
    float*        bufA    = ws + 100352 + 100608 + 512 + 512 + 128 + 1600000; // N*64 fp32 region
    float*        bufB    = bufA + (size_t)N_NODES * HID_F;                   // N*64 fp32 (agg)
    unsigned int*  aux  = (unsigned int*)bufA;     // CSR-build scratch, dead before gemm1
    unsigned short* hsb = (unsigned short*)bufA;   // bf16 hs1, then bf16 hs2 (12.8 MB)
    float* partials = out;                         // NGBLK*128 floats, dead until gather2

    const int* srcv = ei;
    const int* dstv = ei + E_EDGES;

    hipMemsetAsync(coff, 0, (NBUK + 1) * sizeof(int), stream);
    hipMemsetAsync(bnstats, 0, 128 * sizeof(float), stream);

    k_chist  <<<256, 512, 0, stream>>>(dstv, coff);
    k_cscan  <<<1, 512, 0, stream>>>(coff, ccur);
    k_bucket <<<256, 512, 0, stream>>>(srcv, dstv, ccur, aux);
    k_csrnode<<<NBUK, 256, 0, stream>>>(coff, aux, rowptr, dis, csr_src);

    k_gemm1  <<<(N_NODES + 63) / 64, 256, 0, stream>>>(x, W1, dis, hsb);
    k_gather1<<<NGBLK, 256, 0, stream>>>(rowptr, csr_src, hsb, dis, b1, bufB, partials);
    k_bnfinal<<<64, 256, 0, stream>>>(partials, bnstats);
    k_gemm2  <<<(N_NODES + 63) / 64, 256, 0, stream>>>(bufB, W2, dis, bnw, bnb, bnstats, hsb);
    k_gather2<<<NGBLK, 256, 0, stream>>>(rowptr, csr_src, hsb, dis, b2, out);
}

// Round 6
// 254.605 us; speedup vs baseline: 11.7785x; 1.0829x over previous
//
#include <hip/hip_runtime.h>

#define N_NODES 100000
#define E_EDGES 1600000
#define IN_F    128
#define HID_F   64
#define OUT_F   64
#define BN_EPS  1e-5f
#define NBUK    391    // ceil(N/256) coarse buckets (256 nodes each)
#define CHUNK   6250   // E / 256 blocks
#define NGBLK   3125   // N/32 gather blocks (32 nodes per block, 8 lanes/node)
#define NMBLK   1563   // ceil(N/64) gemm blocks

typedef __bf16 bf16x8 __attribute__((ext_vector_type(8)));
typedef float  f32x4  __attribute__((ext_vector_type(4)));

// bf16 helpers ---------------------------------------------------------------
__device__ __forceinline__ float bflo(unsigned int u) { return __uint_as_float(u << 16); }
__device__ __forceinline__ float bfhi(unsigned int u) { return __uint_as_float(u & 0xFFFF0000u); }
__device__ __forceinline__ unsigned int pack2bf(float a, float b) {
    unsigned int ua = __float_as_uint(a), ub = __float_as_uint(b);
    ua = (ua + 0x7fffu + ((ua >> 16) & 1u)) >> 16;          // RNE
    ub = (ub + 0x7fffu + ((ub >> 16) & 1u)) >> 16;
    return ua | (ub << 16);
}
__device__ __forceinline__ unsigned short bf1(float a) {
    unsigned int ua = __float_as_uint(a);
    return (unsigned short)((ua + 0x7fffu + ((ua >> 16) & 1u)) >> 16);
}
#define ADD8(A, u)                                           \
    do {                                                     \
        A[0] += bflo((u).x); A[1] += bfhi((u).x);            \
        A[2] += bflo((u).y); A[3] += bfhi((u).y);            \
        A[4] += bflo((u).z); A[5] += bfhi((u).z);            \
        A[6] += bflo((u).w); A[7] += bfhi((u).w);            \
    } while (0)

// ---------------------------------------------------------------------------
// 1. coarse histogram: chist[dst>>8]++ via LDS aggregation
__global__ __launch_bounds__(512) void k_chist(const int* __restrict__ dstv,
                                               int* __restrict__ chist) {
    __shared__ int h[NBUK];
    const int tid = threadIdx.x;
    const int e0 = blockIdx.x * CHUNK;
    for (int b = tid; b < NBUK; b += 512) h[b] = 0;
    __syncthreads();
    for (int t = tid; t < CHUNK; t += 512)
        atomicAdd(&h[dstv[e0 + t] >> 8], 1);
    __syncthreads();
    for (int b = tid; b < NBUK; b += 512)
        if (h[b]) atomicAdd(&chist[b], h[b]);
}

// 2. exclusive scan of 391 coarse counts -> coff (in place) + working copy ccur
__global__ __launch_bounds__(512) void k_cscan(int* __restrict__ coff,
                                               int* __restrict__ ccur) {
    __shared__ int sh[512];
    const int tid = threadIdx.x;
    int v = (tid < NBUK) ? coff[tid] : 0;
    sh[tid] = v;
    __syncthreads();
    for (int off = 1; off < 512; off <<= 1) {
        int t = (tid >= off) ? sh[tid - off] : 0;
        __syncthreads();
        sh[tid] += t;
        __syncthreads();
    }
    int excl = sh[tid] - v;
    if (tid < NBUK) { coff[tid] = excl; ccur[tid] = excl; }
    if (tid == 0) coff[NBUK] = E_EDGES;
}

// 3. bucket scatter: aux[pos] = src<<8 | (dst&255), coarse-bucket-grouped.
__global__ __launch_bounds__(512) void k_bucket(const int* __restrict__ srcv,
                                                const int* __restrict__ dstv,
                                                int* __restrict__ ccur,
                                                unsigned int* __restrict__ aux) {
    __shared__ int dl[CHUNK];                  // 25 KB
    __shared__ int hist[NBUK], base[NBUK], lcur[NBUK];
    const int tid = threadIdx.x;
    const int e0 = blockIdx.x * CHUNK;
    for (int b = tid; b < NBUK; b += 512) hist[b] = 0;
    __syncthreads();
    for (int t = tid; t < CHUNK; t += 512) {
        int d = dstv[e0 + t];
        dl[t] = d;
        atomicAdd(&hist[d >> 8], 1);
    }
    __syncthreads();
    for (int b = tid; b < NBUK; b += 512) {
        int h = hist[b];
        if (h) base[b] = atomicAdd(&ccur[b], h);
        lcur[b] = 0;
    }
    __syncthreads();
    for (int t = tid; t < CHUNK; t += 512) {
        int d = dl[t];
        int b = d >> 8;
        int off = atomicAdd(&lcur[b], 1);
        aux[base[b] + off] = ((unsigned int)srcv[e0 + t] << 8) | (unsigned int)(d & 255);
    }
}

// 4. per-bucket: per-node counts (LDS) -> rowptr + dis, then fine CSR placement.
__global__ __launch_bounds__(256) void k_csrnode(const int* __restrict__ coff,
                                                 const unsigned int* __restrict__ aux,
                                                 int* __restrict__ rowptr,
                                                 float* __restrict__ dis,
                                                 int* __restrict__ csr_src) {
    __shared__ int c0[256], sc[256], cur[256];
    const int tid = threadIdx.x;
    const int n0 = blockIdx.x * 256;
    const int nn = min(256, N_NODES - n0);
    const int estart = coff[blockIdx.x];
    const int eend   = coff[blockIdx.x + 1];
    c0[tid] = 0;
    __syncthreads();
    for (int e = estart + tid; e < eend; e += 256)
        atomicAdd(&c0[aux[e] & 255], 1);
    __syncthreads();
    int v = c0[tid];
    sc[tid] = v;
    __syncthreads();
    for (int off = 1; off < 256; off <<= 1) {
        int t = (tid >= off) ? sc[tid - off] : 0;
        __syncthreads();
        sc[tid] += t;
        __syncthreads();
    }
    int excl = sc[tid] - v;
    if (tid < nn) {
        int p = estart + excl;
        rowptr[n0 + tid] = p;
        cur[tid] = p;
        dis[n0 + tid] = rsqrtf((float)v + 1.0f);
    }
    if (blockIdx.x == NBUK - 1 && tid == 0) rowptr[N_NODES] = E_EDGES;
    __syncthreads();
    for (int e = estart + tid; e < eend; e += 256) {
        unsigned int u = aux[e];
        int pos = atomicAdd(&cur[u & 255], 1);
        csr_src[pos] = (int)(u >> 8);
    }
}

// ---------------------------------------------------------------------------
// 5. MFMA: hs1 = bf16( dis * (x @ W1) ); 64-row tile, 4 waves, 16x16x32 bf16.
//    A LDS rows padded to 136 bf16 (272 B = 17*16B, odd units -> conflict-free b128).
__global__ __launch_bounds__(256) void k_gemm1(const float* __restrict__ x,
                                               const float* __restrict__ W1,
                                               const float* __restrict__ dis,
                                               unsigned short* __restrict__ hs1) {
    __shared__ unsigned short Asb[64 * 136];   // 17408 B
    __shared__ unsigned short Btb[64 * 136];   // 17408 B (Bt[n][k])
    __shared__ unsigned short Cc[64 * 72];     // 9216 B
    __shared__ float disS[64];
    const int tid = threadIdx.x;
    const int r0 = blockIdx.x * 64;

    if (tid < 64) disS[tid] = (r0 + tid < N_NODES) ? dis[r0 + tid] : 0.f;

    // stage A: 64 rows x 128 cols fp32 -> bf16 LDS
    const float4* x4 = (const float4*)x;
#pragma unroll
    for (int p = 0; p < 4; ++p) {
        int idx8 = p * 256 + tid;              // 8-elem chunk id (1024 total)
        int row = idx8 >> 4, c8 = idx8 & 15;
        float4 v0 = make_float4(0.f, 0.f, 0.f, 0.f), v1 = v0;
        if (r0 + row < N_NODES) {
            v0 = x4[(size_t)(r0 + row) * 32 + c8 * 2];
            v1 = x4[(size_t)(r0 + row) * 32 + c8 * 2 + 1];
        }
        uint4 u;
        u.x = pack2bf(v0.x, v0.y); u.y = pack2bf(v0.z, v0.w);
        u.z = pack2bf(v1.x, v1.y); u.w = pack2bf(v1.z, v1.w);
        *(uint4*)&Asb[row * 136 + c8 * 8] = u;
    }
    // stage Bt[n][k] = W1[k][n]
    for (int idx = tid; idx < IN_F * HID_F; idx += 256) {
        int k = idx >> 6, n = idx & 63;
        Btb[n * 136 + k] = bf1(W1[idx]);
    }
    __syncthreads();

    const int wv = tid >> 6, lane = tid & 63;
    const int m = lane & 15, quad = lane >> 4;
    const int arow = wv * 16 + m;
    f32x4 acc[4] = {};
#pragma unroll
    for (int ks = 0; ks < 4; ++ks) {
        int k0 = ks * 32 + quad * 8;
        bf16x8 af = *(const bf16x8*)&Asb[arow * 136 + k0];
#pragma unroll
        for (int c = 0; c < 4; ++c) {
            bf16x8 bfr = *(const bf16x8*)&Btb[(c * 16 + m) * 136 + k0];
            acc[c] = __builtin_amdgcn_mfma_f32_16x16x32_bf16(af, bfr, acc[c], 0, 0, 0);
        }
    }
    // epilogue: dis-scale, pack bf16 into LDS tile, coalesced store
#pragma unroll
    for (int c = 0; c < 4; ++c)
#pragma unroll
        for (int r = 0; r < 4; ++r) {
            int rl = wv * 16 + quad * 4 + r;
            Cc[rl * 72 + c * 16 + m] = bf1(acc[c][r] * disS[rl]);
        }
    __syncthreads();
#pragma unroll
    for (int p = 0; p < 2; ++p) {
        int idx = p * 256 + tid;
        int row = idx >> 3, c8 = idx & 7;
        if (r0 + row < N_NODES)
            *(uint4*)&hs1[(size_t)(r0 + row) * 64 + c8 * 8] = *(uint4*)&Cc[row * 72 + c8 * 8];
    }
}

// ---------------------------------------------------------------------------
// 6. gather conv1 (bf16 rows) + epilogue + per-block BN partials.
__global__ __launch_bounds__(256) void k_gather1(const int* __restrict__ rowptr,
                                                 const int* __restrict__ csr_src,
                                                 const unsigned short* __restrict__ hsb,
                                                 const float* __restrict__ dis,
                                                 const float* __restrict__ b1,
                                                 float* __restrict__ agg,
                                                 float* __restrict__ partials) {
    const int tid = threadIdx.x;
    const int g = tid >> 3, q = tid & 7;
    const int n = blockIdx.x * 32 + g;
    const uint4* __restrict__ hs16 = (const uint4*)hsb;   // row = 8 uint4

    const int start = rowptr[n], end = rowptr[n + 1];
    float A0[8] = {}, A1[8] = {}, A2[8] = {}, A3[8] = {};
    {   // self term
        uint4 u = hs16[(size_t)n * 8 + q];
        ADD8(A0, u);
    }
    int i = start;
    for (; i + 3 < end; i += 4) {
        int s0 = csr_src[i + 0], s1 = csr_src[i + 1];
        int s2 = csr_src[i + 2], s3 = csr_src[i + 3];
        uint4 u0 = hs16[(size_t)s0 * 8 + q];
        uint4 u1 = hs16[(size_t)s1 * 8 + q];
        uint4 u2 = hs16[(size_t)s2 * 8 + q];
        uint4 u3 = hs16[(size_t)s3 * 8 + q];
        ADD8(A0, u0); ADD8(A1, u1); ADD8(A2, u2); ADD8(A3, u3);
    }
    for (; i < end; ++i) {
        uint4 u = hs16[(size_t)csr_src[i] * 8 + q];
        ADD8(A0, u);
    }
    const float d = dis[n];
    const float4 blo = ((const float4*)b1)[q * 2];
    const float4 bhi = ((const float4*)b1)[q * 2 + 1];
    float o[8];
    o[0] = fmaf(d, A0[0] + A1[0] + A2[0] + A3[0], blo.x);
    o[1] = fmaf(d, A0[1] + A1[1] + A2[1] + A3[1], blo.y);
    o[2] = fmaf(d, A0[2] + A1[2] + A2[2] + A3[2], blo.z);
    o[3] = fmaf(d, A0[3] + A1[3] + A2[3] + A3[3], blo.w);
    o[4] = fmaf(d, A0[4] + A1[4] + A2[4] + A3[4], bhi.x);
    o[5] = fmaf(d, A0[5] + A1[5] + A2[5] + A3[5], bhi.y);
    o[6] = fmaf(d, A0[6] + A1[6] + A2[6] + A3[6], bhi.z);
    o[7] = fmaf(d, A0[7] + A1[7] + A2[7] + A3[7], bhi.w);
    float4* ag = (float4*)(agg + (size_t)n * HID_F + q * 8);
    ag[0] = make_float4(o[0], o[1], o[2], o[3]);
    ag[1] = make_float4(o[4], o[5], o[6], o[7]);

    __shared__ float4 redA[256], redB[256];   // 8 KB
    redA[tid] = make_float4(o[0], o[1], o[2], o[3]);
    redB[tid] = make_float4(o[4], o[5], o[6], o[7]);
    __syncthreads();
    for (int s = 128; s >= 8; s >>= 1) {
        if (tid < s) {
            redA[tid].x += redA[tid + s].x; redA[tid].y += redA[tid + s].y;
            redA[tid].z += redA[tid + s].z; redA[tid].w += redA[tid + s].w;
            redB[tid].x += redB[tid + s].x; redB[tid].y += redB[tid + s].y;
            redB[tid].z += redB[tid + s].z; redB[tid].w += redB[tid + s].w;
        }
        __syncthreads();
    }
    float4* pr = (float4*)(partials + (size_t)blockIdx.x * 128);
    if (tid < 8) { pr[tid * 2] = redA[tid]; pr[tid * 2 + 1] = redB[tid]; }
    __syncthreads();
    redA[tid] = make_float4(o[0] * o[0], o[1] * o[1], o[2] * o[2], o[3] * o[3]);
    redB[tid] = make_float4(o[4] * o[4], o[5] * o[5], o[6] * o[6], o[7] * o[7]);
    __syncthreads();
    for (int s = 128; s >= 8; s >>= 1) {
        if (tid < s) {
            redA[tid].x += redA[tid + s].x; redA[tid].y += redA[tid + s].y;
            redA[tid].z += redA[tid + s].z; redA[tid].w += redA[tid + s].w;
            redB[tid].x += redB[tid + s].x; redB[tid].y += redB[tid + s].y;
            redB[tid].z += redB[tid + s].z; redB[tid].w += redB[tid + s].w;
        }
        __syncthreads();
    }
    if (tid < 8) { pr[16 + tid * 2] = redA[tid]; pr[16 + tid * 2 + 1] = redB[tid]; }
}

// 6b. reduce partials[NGBLK][128] -> bnstats[128]
__global__ __launch_bounds__(256) void k_bnfinal(const float* __restrict__ partials,
                                                 float* __restrict__ bnstats) {
    const int tid = threadIdx.x;
    const int col = tid & 127;
    const int half = tid >> 7;
    float s = 0.f;
    for (int r = blockIdx.x * 2 + half; r < NGBLK; r += 128)
        s += partials[(size_t)r * 128 + col];
    __shared__ float sh[256];
    sh[tid] = s;
    __syncthreads();
    if (tid < 128) unsafeAtomicAdd(&bnstats[col], sh[tid] + sh[tid + 128]);
}

// ---------------------------------------------------------------------------
// 7. MFMA: hs2 = bf16( dis * (relu(BN(agg1)) @ W2) ); K=64.
__global__ __launch_bounds__(256) void k_gemm2(const float* __restrict__ agg1,
                                               const float* __restrict__ W2,
                                               const float* __restrict__ dis,
                                               const float* __restrict__ bnw,
                                               const float* __restrict__ bnb,
                                               const float* __restrict__ bnstats,
                                               unsigned short* __restrict__ hs2) {
    __shared__ unsigned short Ab[64 * 72];     // 9216 B (rows 144 B = 9*16B, odd)
    __shared__ unsigned short Bt2[64 * 72];    // 9216 B
    __shared__ unsigned short Cc[64 * 72];     // 9216 B
    __shared__ float scale_s[64], shift_s[64], disS[64];
    const int tid = threadIdx.x;
    const int r0 = blockIdx.x * 64;

    if (tid < 64) {
        const float invN = 1.0f / (float)N_NODES;
        float mean = bnstats[tid] * invN;
        float var  = bnstats[64 + tid] * invN - mean * mean;
        float sc   = bnw[tid] * rsqrtf(var + BN_EPS);
        scale_s[tid] = sc;
        shift_s[tid] = fmaf(-mean, sc, bnb[tid]);
        disS[tid] = (r0 + tid < N_NODES) ? dis[r0 + tid] : 0.f;
    }
    for (int idx = tid; idx < HID_F * OUT_F; idx += 256) {
        int k = idx >> 6, n = idx & 63;
        Bt2[n * 72 + k] = bf1(W2[idx]);
    }
    __syncthreads();   // scale_s/shift_s ready before A-stage uses them

    const float4* a4 = (const float4*)agg1;
#pragma unroll
    for (int p = 0; p < 4; ++p) {
        int idx4 = p * 256 + tid;              // float4 id (1024 total)
        int row = idx4 >> 4, c4 = idx4 & 15;
        float4 v = make_float4(0.f, 0.f, 0.f, 0.f);
        if (r0 + row < N_NODES) v = a4[(size_t)(r0 + row) * 16 + c4];
        int k0 = c4 * 4;
        v.x = fmaxf(fmaf(v.x, scale_s[k0 + 0], shift_s[k0 + 0]), 0.f);
        v.y = fmaxf(fmaf(v.y, scale_s[k0 + 1], shift_s[k0 + 1]), 0.f);
        v.z = fmaxf(fmaf(v.z, scale_s[k0 + 2], shift_s[k0 + 2]), 0.f);
        v.w = fmaxf(fmaf(v.w, scale_s[k0 + 3], shift_s[k0 + 3]), 0.f);
        uint2 u;
        u.x = pack2bf(v.x, v.y); u.y = pack2bf(v.z, v.w);
        *(uint2*)&Ab[row * 72 + c4 * 4] = u;
    }
    __syncthreads();

    const int wv = tid >> 6, lane = tid & 63;
    const int m = lane & 15, quad = lane >> 4;
    const int arow = wv * 16 + m;
    f32x4 acc[4] = {};
#pragma unroll
    for (int ks = 0; ks < 2; ++ks) {
        int k0 = ks * 32 + quad * 8;
        bf16x8 af = *(const bf16x8*)&Ab[arow * 72 + k0];
#pragma unroll
        for (int c = 0; c < 4; ++c) {
            bf16x8 bfr = *(const bf16x8*)&Bt2[(c * 16 + m) * 72 + k0];
            acc[c] = __builtin_amdgcn_mfma_f32_16x16x32_bf16(af, bfr, acc[c], 0, 0, 0);
        }
    }
#pragma unroll
    for (int c = 0; c < 4; ++c)
#pragma unroll
        for (int r = 0; r < 4; ++r) {
            int rl = wv * 16 + quad * 4 + r;
            Cc[rl * 72 + c * 16 + m] = bf1(acc[c][r] * disS[rl]);
        }
    __syncthreads();
#pragma unroll
    for (int p = 0; p < 2; ++p) {
        int idx = p * 256 + tid;
        int row = idx >> 3, c8 = idx & 7;
        if (r0 + row < N_NODES)
            *(uint4*)&hs2[(size_t)(r0 + row) * 64 + c8 * 8] = *(uint4*)&Cc[row * 72 + c8 * 8];
    }
}

// ---------------------------------------------------------------------------
// 8. gather conv2 (bf16 rows) + final epilogue -> fp32 out
__global__ __launch_bounds__(256) void k_gather2(const int* __restrict__ rowptr,
                                                 const int* __restrict__ csr_src,
                                                 const unsigned short* __restrict__ hsb,
                                                 const float* __restrict__ dis,
                                                 const float* __restrict__ b2,
                                                 float* __restrict__ out) {
    const int tid = threadIdx.x;
    const int g = tid >> 3, q = tid & 7;
    const int n = blockIdx.x * 32 + g;
    const uint4* __restrict__ hs16 = (const uint4*)hsb;

    const int start = rowptr[n], end = rowptr[n + 1];
    float A0[8] = {}, A1[8] = {}, A2[8] = {}, A3[8] = {};
    {
        uint4 u = hs16[(size_t)n * 8 + q];
        ADD8(A0, u);
    }
    int i = start;
    for (; i + 3 < end; i += 4) {
        int s0 = csr_src[i + 0], s1 = csr_src[i + 1];
        int s2 = csr_src[i + 2], s3 = csr_src[i + 3];
        uint4 u0 = hs16[(size_t)s0 * 8 + q];
        uint4 u1 = hs16[(size_t)s1 * 8 + q];
        uint4 u2 = hs16[(size_t)s2 * 8 + q];
        uint4 u3 = hs16[(size_t)s3 * 8 + q];
        ADD8(A0, u0); ADD8(A1, u1); ADD8(A2, u2); ADD8(A3, u3);
    }
    for (; i < end; ++i) {
        uint4 u = hs16[(size_t)csr_src[i] * 8 + q];
        ADD8(A0, u);
    }
    const float d = dis[n];
    const float4 blo = ((const float4*)b2)[q * 2];
    const float4 bhi = ((const float4*)b2)[q * 2 + 1];
    float4 o0, o1;
    o0.x = fmaf(d, A0[0] + A1[0] + A2[0] + A3[0], blo.x);
    o0.y = fmaf(d, A0[1] + A1[1] + A2[1] + A3[1], blo.y);
    o0.z = fmaf(d, A0[2] + A1[2] + A2[2] + A3[2], blo.z);
    o0.w = fmaf(d, A0[3] + A1[3] + A2[3] + A3[3], blo.w);
    o1.x = fmaf(d, A0[4] + A1[4] + A2[4] + A3[4], bhi.x);
    o1.y = fmaf(d, A0[5] + A1[5] + A2[5] + A3[5], bhi.y);
    o1.z = fmaf(d, A0[6] + A1[6] + A2[6] + A3[6], bhi.z);
    o1.w = fmaf(d, A0[7] + A1[7] + A2[7] + A3[7], bhi.w);
    float4* op = (float4*)(out + (size_t)n * OUT_F + q * 8);
    op[0] = o0;
    op[1] = o1;
}

// ---------------------------------------------------------------------------
extern "C" void kernel_launch(void* const* d_in, const int* in_sizes, int n_in,
                              void* d_out, int out_size, void* d_ws, size_t ws_size,
                              hipStream_t stream) {
    const float* x   = (const float*)d_in[0];
    const int*   ei  = (const int*)d_in[1];
    const float* W1  = (const float*)d_in[2];
    const float* b1  = (const float*)d_in[3];
    const float* bnw = (const float*)d_in[4];
    const float* bnb = (const float*)d_in[5];
    const float* W2  = (const float*)d_in[6];
    const float* b2  = (const float*)d_in[7];
    float* out = (float*)d_out;

    // workspace layout (floats, 16B-aligned segments):
    float* ws = (float*)d_ws;
    float*        dis     = ws;                               // 100352
    int*          rowptr  = (int*)(ws + 100352);              // 100608 (N+1 used)
    int*          coff    = (int*)(ws + 100352 + 100608);     // 512 (NBUK+1 used)
    int*          ccur    = (int*)(ws + 100352 + 100608 + 512);          // 512
    float*        bnstats = ws + 100352 + 100608 + 512 + 512;            // 128
    int*          csr_src = (int*)(ws + 100352 + 100608 + 512 + 512 + 128); // 1.6M
    float*        bufA    = ws + 100352 + 100608 + 512 + 512 + 128 + 1600000; // N*64 fp32 region
    float*        bufB    = bufA + (size_t)N_NODES * HID_F;                   // N*64 fp32 (agg)
    unsigned int*  aux  = (unsigned int*)bufA;     // CSR-build scratch, dead before gemm1
    unsigned short* hsb = (unsigned short*)bufA;   // bf16 hs1, then bf16 hs2 (12.8 MB)
    float* partials = out;                         // NGBLK*128 floats, dead until gather2

    const int* srcv = ei;
    const int* dstv = ei + E_EDGES;

    hipMemsetAsync(coff, 0, (NBUK + 1) * sizeof(int), stream);
    hipMemsetAsync(bnstats, 0, 128 * sizeof(float), stream);

    k_chist  <<<256, 512, 0, stream>>>(dstv, coff);
    k_cscan  <<<1, 512, 0, stream>>>(coff, ccur);
    k_bucket <<<256, 512, 0, stream>>>(srcv, dstv, ccur, aux);
    k_csrnode<<<NBUK, 256, 0, stream>>>(coff, aux, rowptr, dis, csr_src);

    k_gemm1  <<<NMBLK, 256, 0, stream>>>(x, W1, dis, hsb);
    k_gather1<<<NGBLK, 256, 0, stream>>>(rowptr, csr_src, hsb, dis, b1, bufB, partials);
    k_bnfinal<<<64, 256, 0, stream>>>(partials, bnstats);
    k_gemm2  <<<NMBLK, 256, 0, stream>>>(bufB, W2, dis, bnw, bnb, bnstats, hsb);
    k_gather2<<<NGBLK, 256, 0, stream>>>(rowptr, csr_src, hsb, dis, b2, out);
}